// Round 13
// baseline (1710.432 us; speedup 1.0000x reference)
//
#include <hip/hip_runtime.h>
#include <hip/hip_bf16.h>

typedef __attribute__((ext_vector_type(8))) _Float16 half8;
typedef __attribute__((ext_vector_type(4))) _Float16 half4;
typedef __attribute__((ext_vector_type(4))) float f32x4;
typedef __attribute__((ext_vector_type(4))) unsigned int u32x4;

#define VOC 32000
#define EMB 512
#define HID 1024
#define SS  256
#define NROW 4096   // S*B rows, ordered r = t*16 + b
#define CHK 43      // 16B chunks per producer block (6 halves + u32 tag each)
#define CSTRIDE 64  // chunk slots per producer (stride)
#define SLOTB (64 * CSTRIDE * 16)   // bytes per slot = 65536
#define NS 4        // slots per h buffer (quad buffer: WAR slack 3)
#define SPIN (1 << 16)
#define ROWH 264    // LDS halves per producer row (512B data + 16B pad)

__device__ __forceinline__ float sigf(float x) {
    return 1.f / (1.f + __expf(-x));
}
__device__ __forceinline__ float tanh_c(float x) {
    x = fminf(fmaxf(x, -15.f), 15.f);
    float e = __expf(2.f * x);
    return (e - 1.f) / (e + 1.f);
}

// ---- MALL-coherent primitives (bypass L1+L2) ----
__device__ __forceinline__ u32x4 ldg_u4_cc(const void* p) {   // issue only, no wait
    u32x4 r;
    asm volatile("global_load_dwordx4 %0, %1, off sc0 sc1" : "=v"(r) : "v"(p));
    return r;
}
__device__ __forceinline__ void stg_u4_cc(void* p, u32x4 v) {
    asm volatile("global_store_dwordx4 %0, %1, off sc0 sc1" :: "v"(p), "v"(v) : "memory");
}
__device__ __forceinline__ void stg_u32_cc(unsigned* p, unsigned v) {
    asm volatile("global_store_dword %0, %1, off sc0 sc1" :: "v"(p), "v"(v) : "memory");
}
__device__ __forceinline__ unsigned ldg_u32_cc(const unsigned* p) {
    unsigned v;
    asm volatile("global_load_dword %0, %1, off sc0 sc1\n\ts_waitcnt vmcnt(0)"
                 : "=v"(v) : "v"(p) : "memory");
    return v;
}
// force a weight fragment into the AGPR file
__device__ __forceinline__ half8 to_agpr(half8 v) {
    asm volatile("" : "+a"(v));
    return v;
}
// async global->LDS, 16B per lane; lds base must be wave-uniform + lane*16
__device__ __forceinline__ void gload16(const void* g, void* lds) {
    __builtin_amdgcn_global_load_lds(
        (const __attribute__((address_space(1))) unsigned int*)(uintptr_t)g,
        (__attribute__((address_space(3))) unsigned int*)(unsigned int)(uintptr_t)lds,
        16, 0, 0);
}

// ---------------- utility kernels ----------------
__global__ void k_zero(float* p, int n) {
    int i = blockIdx.x * blockDim.x + threadIdx.x;
    int st = gridDim.x * blockDim.x;
    for (; i < n; i += st) p[i] = 0.f;
}

// all five weight conversions fused into one grid-stride kernel
__global__ void k_cvt_all(const float* __restrict__ s0, const float* __restrict__ s1,
                          const float* __restrict__ s2, const float* __restrict__ s3,
                          const float* __restrict__ s4,
                          _Float16* __restrict__ d0, _Float16* __restrict__ d1,
                          _Float16* __restrict__ d2, _Float16* __restrict__ d3,
                          _Float16* __restrict__ d4) {
    const int n0 = 4096 * 512 / 4;
    const int n1 = 4096 * 1024 / 4;
    const int n4 = VOC * 1024 / 4;
    const int nT = n0 + 3 * n1 + n4;
    int i = blockIdx.x * 256 + threadIdx.x;
    int st = gridDim.x * 256;
    for (; i < nT; i += st) {
        const float* s; _Float16* d; int k = i;
        if (k < n0) { s = s0; d = d0; }
        else {
            k -= n0;
            if (k < n1) { s = s1; d = d1; }
            else {
                k -= n1;
                if (k < n1) { s = s2; d = d2; }
                else {
                    k -= n1;
                    if (k < n1) { s = s3; d = d3; }
                    else { k -= n1; s = s4; d = d4; }
                }
            }
        }
        float4 v = ((const float4*)s)[k];
        half4 o = {(_Float16)v.x, (_Float16)v.y, (_Float16)v.z, (_Float16)v.w};
        ((half4*)d)[k] = o;
    }
}

__global__ void k_bias(const float* bi1, const float* bh1,
                       const float* bi2, const float* bh2,
                       float* b1, float* b2) {
    int i = blockIdx.x * blockDim.x + threadIdx.x;
    if (i < 4 * HID) { b1[i] = bi1[i] + bh1[i]; b2[i] = bi2[i] + bh2[i]; }
}

// gather embedding rows -> f16 A [4096][512], row r = t*16+b
__global__ void k_embed(const int* __restrict__ tok, const float* __restrict__ emb,
                        _Float16* __restrict__ A) {
    int idx = blockIdx.x * 256 + threadIdx.x;
    if (idx >= NROW * (EMB / 4)) return;
    int r = idx >> 7, c4 = idx & 127;
    int t = r >> 4, b = r & 15;
    int token = tok[b * SS + t];
    float4 v = ((const float4*)(emb + (size_t)token * EMB))[c4];
    half4 o = {(_Float16)v.x, (_Float16)v.y, (_Float16)v.z, (_Float16)v.w};
    ((half4*)(A + (size_t)r * EMB))[c4] = o;
}

// ---------------- 256x256 / BK=64 pipelined GEMM (T3+T4+T2, proven r12) --------------
// 512 thr = 8 waves (2M x 4N); per-wave out 128x64 (8x4 16x16 frags).
// LDS 128KB: 2 bufs x (A[256][64] + B[256][64]) f16, XOR-swizzled columns
// (slot = kc ^ (row&7)) applied on the GLOBAL source (write) and on ds_read.
// Counted vmcnt keeps 4 loads in flight across barriers (never 0 mid-loop).
template <int F16OUT>
__global__ __launch_bounds__(512, 1) void k_gemm8(
    const _Float16* __restrict__ A, const _Float16* __restrict__ B,
    const float* __restrict__ bias, float* __restrict__ Cf,
    _Float16* __restrict__ Ch, int M, int N, int K, int scatter) {
    __shared__ __align__(16) char smem[131072];
    int tid = threadIdx.x;
    int wave = tid >> 6, lane = tid & 63;
    int wm = wave >> 2, wn = wave & 3;
    int nbx = gridDim.x;
    int lin = blockIdx.y * nbx + blockIdx.x;
    {   // bijective XCD swizzle (grid % 8 == 0 for our shapes)
        int n = nbx * gridDim.y;
        if ((n & 7) == 0) { int cpx = n >> 3; lin = (lin & 7) * cpx + (lin >> 3); }
    }
    int bRow = (lin / nbx) * 256, bCol = (lin % nbx) * 256;
    int nt = K >> 6;
    int lrow = lane & 15, kq = lane >> 4;

    auto stage = [&](int mat, int h, int t) {
        const _Float16* src = mat ? B : A;
        int r0 = mat ? bCol : bRow;
        char* dst = smem + (size_t)(t & 1) * 65536 + mat * 32768 + h * 16384;
#pragma unroll
        for (int j = 0; j < 2; ++j) {
            int ci = j * 512 + tid;
            int row = ci >> 3, slot = ci & 7;
            int grow = h * 128 + row;
            int gsl = slot ^ (row & 7);
            gload16(src + (size_t)(r0 + grow) * K + t * 64 + gsl * 8, dst + ci * 16);
        }
    };
    auto rdA = [&](int bf, int mi, int kk) -> half8 {
        int r = wm * 128 + mi * 16 + lrow;
        int sl = (kk * 4 + kq) ^ (lrow & 7);
        return *(const half8*)(smem + (size_t)bf * 65536 + r * 128 + sl * 16);
    };
    auto rdB = [&](int bf, int ni, int kk) -> half8 {
        int r = wn * 64 + ni * 16 + lrow;
        int sl = (kk * 4 + kq) ^ (lrow & 7);
        return *(const half8*)(smem + (size_t)bf * 65536 + 32768 + r * 128 + sl * 16);
    };

    f32x4 acc[8][4] = {};

    // prologue: B0(0) A0(0) B1(0) A1(0) B0(1) A0(1)
    stage(1, 0, 0); stage(0, 0, 0); stage(1, 1, 0); stage(0, 1, 0);
    if (nt > 1) { stage(1, 0, 1); stage(0, 0, 1); }

    for (int u = 0; u < nt; ++u) {
        int bf = u & 1;
        if (u + 1 == nt) asm volatile("s_waitcnt vmcnt(0)" ::: "memory");
        else             asm volatile("s_waitcnt vmcnt(4)" ::: "memory");
        __builtin_amdgcn_s_barrier();
        __builtin_amdgcn_sched_barrier(0);
        // ---- R0 ----
        if (u + 1 < nt) stage(1, 1, u + 1);          // B1(u+1)
        half8 a[8][2], b[4][2];
#pragma unroll
        for (int mi = 0; mi < 8; ++mi)
#pragma unroll
            for (int kk = 0; kk < 2; ++kk)
                a[mi][kk] = rdA(bf, mi, kk);
#pragma unroll
        for (int ni = 0; ni < 4; ++ni)
#pragma unroll
            for (int kk = 0; kk < 2; ++kk)
                b[ni][kk] = rdB(bf, ni, kk);
        __builtin_amdgcn_s_setprio(1);
#pragma unroll
        for (int mi = 0; mi < 8; ++mi)
#pragma unroll
            for (int ni = 0; ni < 4; ++ni) {
                acc[mi][ni] = __builtin_amdgcn_mfma_f32_16x16x32_f16(a[mi][0], b[ni][0], acc[mi][ni], 0, 0, 0);
                acc[mi][ni] = __builtin_amdgcn_mfma_f32_16x16x32_f16(a[mi][1], b[ni][1], acc[mi][ni], 0, 0, 0);
            }
        __builtin_amdgcn_s_setprio(0);
        asm volatile("s_waitcnt lgkmcnt(0)" ::: "memory");
        __builtin_amdgcn_s_barrier();
        __builtin_amdgcn_sched_barrier(0);
        // ---- R1 ----
        if (u + 1 < nt) stage(0, 1, u + 1);          // A1(u+1)
        if (u + 2 < nt) { stage(1, 0, u + 2); stage(0, 0, u + 2); }  // B0,A0(u+2)
    }

    // epilogue
    float bv[4];
#pragma unroll
    for (int ni = 0; ni < 4; ++ni)
        bv[ni] = bias[bCol + wn * 64 + ni * 16 + lrow];
#pragma unroll
    for (int mi = 0; mi < 8; ++mi)
#pragma unroll
        for (int ni = 0; ni < 4; ++ni)
#pragma unroll
            for (int q = 0; q < 4; ++q) {
                int gr = bRow + wm * 128 + mi * 16 + kq * 4 + q;
                int gc = bCol + wn * 64 + ni * 16 + lrow;
                float v = acc[mi][ni][q] + bv[ni];
                size_t orow = scatter ? (size_t)(((gr & 15) << 8) | (gr >> 4)) : (size_t)gr;
                if (F16OUT) Ch[orow * (size_t)N + gc] = (_Float16)v;
                else        Cf[orow * (size_t)N + gc] = v;
            }
}

// ---------------- tag-poll building blocks ----------------
// Chunk c of producer p holds halves q=6c..6c+5 (q = batch*16 + col16) plus
// tag in dword 3; one 16B store = atomic unit. Thread (sbp=tid>>2, r=tid&3)
// owns chunks r+4j of producer sbp. Accept tag >= exp (monotonic tags).
__device__ __forceinline__ void poll_issue(const char* base, int cnt, u32x4* cv) {
#pragma unroll
    for (int j = 0; j < 11; ++j)
        if (j < cnt) cv[j] = ldg_u4_cc(base + j * 64);
}
__device__ __forceinline__ bool tags_ok(const u32x4* cv, int exp, int cnt) {
    bool ok = true;
#pragma unroll
    for (int j = 0; j < 11; ++j)
        if (j < cnt && (int)cv[j][3] < exp) ok = false;
    return ok;
}
// retry loop; precondition: all prior loads drained (vmcnt==0)
__device__ __forceinline__ void poll_retry(const char* base, int exp, int cnt, u32x4* cv) {
    for (int it = 0; it < SPIN; ++it) {
        bool bad = false;
#pragma unroll
        for (int j = 0; j < 11; ++j)
            if (j < cnt && (int)cv[j][3] < exp) {
                cv[j] = ldg_u4_cc(base + j * 64);
                bad = true;
            }
        if (!bad) break;
        __builtin_amdgcn_s_sleep(1);
        asm volatile("s_waitcnt vmcnt(0)" ::: "memory");
        __builtin_amdgcn_sched_barrier(0);
    }
}
// vectorized LDS stage: chunk's 12 data bytes land contiguous 4-aligned at
// sbp*528 + c*12 -> 3x ds_write_b32, no extraction (round-10 proven layout)
__device__ __forceinline__ void stage_cv(const u32x4* cv, unsigned short* hs,
                                         int sbp, int r, int cnt) {
#pragma unroll
    for (int j = 0; j < 11; ++j)
        if (j < cnt) {
            int c = r + 4 * j;
            unsigned* dst = (unsigned*)((char*)hs + sbp * (2 * ROWH) + c * 12);
            dst[0] = cv[j][0]; dst[1] = cv[j][1]; dst[2] = cv[j][2];
        }
}
// full poll (issue + drain + retry + stage) — L1 path, round-10 exact
__device__ __forceinline__ void poll_stage2(const char* base, int exp, int cnt,
                                            unsigned short* hs, int sbp, int r) {
    u32x4 cv[11];
    poll_issue(base, cnt, cv);
    asm volatile("s_waitcnt vmcnt(0)" ::: "memory");
    __builtin_amdgcn_sched_barrier(0);
    poll_retry(base, exp, cnt, cv);
    stage_cv(cv, hs, sbp, r, cnt);
}

// ---------------- decoupled 2-layer persistent LSTM (v6) ----------------
// 128 blocks x 256 threads; layer = bid>>6, sb = bid&63; block owns h-cols
// [sb*16,sb*16+16), wave w = gate w. h(t) -> slot t&3, tag t+1. Consumers
// poll the data's embedded tags. WAR: quad slots + progress flags (L1:
// all-128 >= g-2 pre-publish; L2: own cohort >= s-2). L2 NEW: issues h2+h1
// loads together, first-waits vmcnt(10) (retires exactly the h2 set, h1
// stays in flight across the recurrent MFMA phase), h1 tag-check after a
// then-nearly-free vmcnt(0). This avoids r9/r11's flaw (vmcnt(0) first-wait
// drained the h1 set too, adding its issue RTT to the rendezvous).
__global__ __launch_bounds__(256, 1) void k_rnn(
    const _Float16* __restrict__ X,          // [4096][4096] f16: x1@Wih1^T + b1
    const _Float16* __restrict__ Whh1,       // [4096][1024] f16
    const _Float16* __restrict__ Wih2,       // [4096][1024] f16
    const _Float16* __restrict__ Whh2,       // [4096][1024] f16
    const float* __restrict__ b2s,           // [4096] = b_ih2 + b_hh2
    char* __restrict__ h1buf,                // NS slots x 64KB tag-chunks
    char* __restrict__ h2buf,                // NS slots x 64KB tag-chunks
    unsigned* __restrict__ prog,             // 128 slots x 64B progress flags
    _Float16* __restrict__ h2seq) {          // [4096][1024] f16 out
    __shared__ __align__(16) unsigned short hsPA[64 * ROWH];
    __shared__ __align__(16) unsigned short hsPB[64 * ROWH];
    __shared__ float gs[4][1024];
    __shared__ __align__(16) unsigned short hstage[264];
    int tid = threadIdx.x;
    int w = tid >> 6, l = tid & 63;
    int bid = blockIdx.x;
    int layer = bid >> 6, sb = bid & 63;
    int sbp = tid >> 2, r = tid & 3;
    int cnt = (r == 3) ? 10 : 11;
    size_t choff = (size_t)(sbp * CSTRIDE + r) * 16;
    int hp = l >> 5;                          // fragment row parity
    int hoff = (l & 15) * 16 + ((l >> 4) & 1) * 8;

    // ---- weights pinned in AGPRs ----
    half8 wA[32];   // L1: Whh1 ; L2: Wih2
    half8 wB[32];   // L2: Whh2
    {
        const _Float16* base = layer ? Wih2 : Whh1;
        const _Float16* wp = base + (size_t)(w * HID + sb * 16 + (l & 15)) * HID + (l >> 4) * 8;
#pragma unroll
        for (int kt = 0; kt < 32; ++kt)
            wA[kt] = to_agpr(*(const half8*)(wp + kt * 32));
        if (layer) {
            const _Float16* wq = Whh2 + (size_t)(w * HID + sb * 16 + (l & 15)) * HID + (l >> 4) * 8;
#pragma unroll
            for (int kt = 0; kt < 32; ++kt)
                wB[kt] = to_agpr(*(const half8*)(wq + kt * 32));
        }
    }
    float bias_v = layer ? b2s[w * HID + sb * 16 + (l & 15)] : 0.f;

    int eb = tid >> 4, ecol = tid & 15;
    int gidx = ((eb >> 2) * 16 + ecol) * 4 + (eb & 3);
    float creg = 0.f;
    int pc = 0;

    if (!layer) {
        // ======= layer 1: g = 0..255; h1(g) from X(g) and h1(g-1) ===========
        const _Float16* xbase = X + (size_t)w * HID + sb * 16 + (l & 15);
        int bq = (l >> 4) * 4;
        f32x4 xreg;
        {
            const _Float16* xp = xbase + (size_t)bq * 4096;
            xreg[0] = (float)xp[0]; xreg[1] = (float)xp[4096];
            xreg[2] = (float)xp[8192]; xreg[3] = (float)xp[12288];
        }
        for (int g = 0; g < SS; ++g) {
            int tn = (g + 1 < SS) ? g + 1 : SS - 1;
            const _Float16* xp = xbase + (size_t)(tn * 16 + bq) * 4096;
            float xn0 = (float)xp[0], xn1 = (float)xp[4096],
                  xn2 = (float)xp[8192], xn3 = (float)xp[12288];

            poll_stage2(h1buf + ((g - 1) & 3) * SLOTB + choff, g, cnt, hsPA, sbp, r);
            __syncthreads();
            if (tid == 0) stg_u32_cc(prog + (size_t)bid * 16, (unsigned)(g + 1));

            f32x4 a0 = xreg, a1 = {}, a2 = {}, a3 = {};
#pragma unroll
            for (int c = 0; c < 4; ++c) {
                half8 ha[8];
#pragma unroll
                for (int j = 0; j < 8; ++j)
                    ha[j] = *(const half8*)(hsPA + (2 * (c * 8 + j) + hp) * ROWH + hoff);
#pragma unroll
                for (int j = 0; j < 8; ++j) {
                    f32x4* ac = (j & 3) == 0 ? &a0 : (j & 3) == 1 ? &a1 : (j & 3) == 2 ? &a2 : &a3;
                    *ac = __builtin_amdgcn_mfma_f32_16x16x32_f16(ha[j], wA[c * 8 + j], *ac, 0, 0, 0);
                }
            }
            a0 = (a0 + a1) + (a2 + a3);

            *(f32x4*)(&gs[w][l * 4]) = a0;
            __syncthreads();

            float gi = gs[0][gidx], gf = gs[1][gidx], gg = gs[2][gidx], go = gs[3][gidx];
            float cn = sigf(gf) * creg + sigf(gi) * tanh_c(gg);
            float hn = sigf(go) * tanh_c(cn);
            creg = cn;
            _Float16 hh = (_Float16)hn;
            unsigned short hu;
            __builtin_memcpy(&hu, &hh, 2);
            hstage[eb * 16 + ecol] = hu;
            xreg[0] = xn0; xreg[1] = xn1; xreg[2] = xn2; xreg[3] = xn3;
            __syncthreads();

            if (tid < 128 && pc < g - 2) {
                const unsigned* pp = prog + (size_t)tid * 16;
                for (int it = 0; it < SPIN; ++it) {
                    unsigned v = ldg_u32_cc(pp);
                    if ((int)v >= g - 2) { pc = (int)v; break; }
                    __builtin_amdgcn_s_sleep(1);
                }
            }
            __syncthreads();
            if (w == 0 && l < CHK) {
                const unsigned* hsu = (const unsigned*)hstage;
                u32x4 pv;
                pv[0] = hsu[l * 3]; pv[1] = hsu[l * 3 + 1]; pv[2] = hsu[l * 3 + 2];
                pv[3] = (unsigned)(g + 1);
                stg_u4_cc(h1buf + (g & 3) * SLOTB + (size_t)(sb * CSTRIDE + l) * 16, pv);
            }
        }
    } else {
        // ======= layer 2: s = 0..255; h2(s) from h1(s) and h2(s-1) ==========
        for (int s = 0; s < SS; ++s) {
            const char* baseB = h2buf + ((s - 1) & 3) * SLOTB + choff;
            const char* baseA = h1buf + (s & 3) * SLOTB + choff;
            u32x4 cvB[11], cvA[11];
            poll_issue(baseB, cnt, cvB);      // h2(s-1): rendezvous
            poll_issue(baseA, cnt, cvA);      // h1(s): published a step ago
            // retire exactly the h2 set; h1 loads stay in flight
            asm volatile("s_waitcnt vmcnt(10)" ::: "memory");
            __builtin_amdgcn_sched_barrier(0);
            if (!tags_ok(cvB, s, cnt)) {      // rare: full drain + retry
                asm volatile("s_waitcnt vmcnt(0)" ::: "memory");
                __builtin_amdgcn_sched_barrier(0);
                poll_retry(baseB, s, cnt, cvB);
            }
            stage_cv(cvB, hsPB, sbp, r, cnt);
            __syncthreads();                  // hsPB ready

            f32x4 a0 = {bias_v, bias_v, bias_v, bias_v}, a1 = {}, a2 = {}, a3 = {};
#pragma unroll
            for (int c = 0; c < 4; ++c) {     // recurrent: h2 x Whh2 (LDS-only)
                half8 ha[8];
#pragma unroll
                for (int j = 0; j < 8; ++j)
                    ha[j] = *(const half8*)(hsPB + (2 * (c * 8 + j) + hp) * ROWH + hoff);
#pragma unroll
                for (int j = 0; j < 8; ++j) {
                    f32x4* ac = (j & 3) == 0 ? &a0 : (j & 3) == 1 ? &a1 : (j & 3) == 2 ? &a2 : &a3;
                    *ac = __builtin_amdgcn_mfma_f32_16x16x32_f16(ha[j], wB[c * 8 + j], *ac, 0, 0, 0);
                }
            }
            // h1 loads have aged through the MFMA phase: drain is ~free
            asm volatile("s_waitcnt vmcnt(0)" ::: "memory");
            __builtin_amdgcn_sched_barrier(0);
            if (!tags_ok(cvA, s + 1, cnt)) poll_retry(baseA, s + 1, cnt, cvA);
            stage_cv(cvA, hsPA, sbp, r, cnt);
            __syncthreads();                  // hsPA ready
            if (tid == 0) stg_u32_cc(prog + (size_t)bid * 16, (unsigned)(s + 1));

#pragma unroll
            for (int c = 0; c < 4; ++c) {     // input path: h1 x Wih2
                half8 ha[8];
#pragma unroll
                for (int j = 0; j < 8; ++j)
                    ha[j] = *(const half8*)(hsPA + (2 * (c * 8 + j) + hp) * ROWH + hoff);
#pragma unroll
                for (int j = 0; j < 8; ++j) {
                    f32x4* ac = (j & 3) == 0 ? &a0 : (j & 3) == 1 ? &a1 : (j & 3) == 2 ? &a2 : &a3;
                    *ac = __builtin_amdgcn_mfma_f32_16x16x32_f16(ha[j], wA[c * 8 + j], *ac, 0, 0, 0);
                }
            }
            a0 = (a0 + a1) + (a2 + a3);

            *(f32x4*)(&gs[w][l * 4]) = a0;
            __syncthreads();

            float gi = gs[0][gidx], gf = gs[1][gidx], gg = gs[2][gidx], go = gs[3][gidx];
            float cn = sigf(gf) * creg + sigf(gi) * tanh_c(gg);
            float hn = sigf(go) * tanh_c(cn);
            creg = cn;
            _Float16 hh = (_Float16)hn;
            unsigned short hu;
            __builtin_memcpy(&hu, &hh, 2);
            hstage[eb * 16 + ecol] = hu;
            __syncthreads();

            if (tid < 64 && pc < s - 2) {
                const unsigned* pp = prog + (size_t)(64 + tid) * 16;
                for (int it = 0; it < SPIN; ++it) {
                    unsigned v = ldg_u32_cc(pp);
                    if ((int)v >= s - 2) { pc = (int)v; break; }
                    __builtin_amdgcn_s_sleep(1);
                }
            }
            __syncthreads();
            if (w == 0 && l < CHK) {
                const unsigned* hsu = (const unsigned*)hstage;
                u32x4 pv;
                pv[0] = hsu[l * 3]; pv[1] = hsu[l * 3 + 1]; pv[2] = hsu[l * 3 + 2];
                pv[3] = (unsigned)(s + 1);
                stg_u4_cc(h2buf + (s & 3) * SLOTB + (size_t)(sb * CSTRIDE + l) * 16, pv);
            }
            if (w == 1 && l < 32) {
                half8 hv = *(const half8*)((const char*)hstage + l * 16);
                *(half8*)(h2seq + (size_t)(s * 16 + (l >> 1)) * HID + sb * 16 + (l & 1) * 8) = hv;
            }
        }
    }
}

// ---------------- fused log-softmax, f32 in-place ----------------
__global__ __launch_bounds__(320) void k_lsm_f(float* __restrict__ logits) {
    int r = blockIdx.x, tid = threadIdx.x;
    float* row = logits + (size_t)r * VOC;
    f32x4 v[25];
    float m = -3.4e38f;
#pragma unroll
    for (int j = 0; j < 25; ++j) {
        v[j] = ((const f32x4*)row)[tid + 320 * j];
        m = fmaxf(fmaxf(fmaxf(m, v[j][0]), fmaxf(v[j][1], v[j][2])), v[j][3]);
    }
#pragma unroll
    for (int off = 1; off < 64; off <<= 1) m = fmaxf(m, __shfl_xor(m, off));
    __shared__ float sm[5], ssum[5];
    int wv = tid >> 6;
    if ((tid & 63) == 0) sm[wv] = m;
    __syncthreads();
    m = fmaxf(fmaxf(fmaxf(sm[0], sm[1]), fmaxf(sm[2], sm[3])), sm[4]);
    float s = 0.f;
#pragma unroll
    for (int j = 0; j < 25; ++j)
        s += (__expf(v[j][0] - m) + __expf(v[j][1] - m)) +
             (__expf(v[j][2] - m) + __expf(v[j][3] - m));
#pragma unroll
    for (int off = 1; off < 64; off <<= 1) s += __shfl_xor(s, off);
    if ((tid & 63) == 0) ssum[wv] = s;
    __syncthreads();
    s = (ssum[0] + ssum[1]) + (ssum[2] + ssum[3]) + ssum[4];
    float lse = m + __logf(s);
#pragma unroll
    for (int j = 0; j < 25; ++j) {
        f32x4 o = v[j];
        o[0] -= lse; o[1] -= lse; o[2] -= lse; o[3] -= lse;
        ((f32x4*)row)[tid + 320 * j] = o;
    }
}

// ---------------- fused log-softmax, f16 in -> f32 out ----------------
__global__ __launch_bounds__(320) void k_lsm_h(const _Float16* __restrict__ lg,
                                               float* __restrict__ out) {
    int r = blockIdx.x, tid = threadIdx.x;
    const half4* row = (const half4*)(lg + (size_t)r * VOC);
    float* orow = out + (size_t)r * VOC;
    half4 v[25];
    float m = -3.4e38f;
#pragma unroll
    for (int j = 0; j < 25; ++j) {
        v[j] = row[tid + 320 * j];
        float a = (float)v[j][0], b = (float)v[j][1], c = (float)v[j][2], d = (float)v[j][3];
        m = fmaxf(fmaxf(fmaxf(m, a), fmaxf(b, c)), d);
    }
#pragma unroll
    for (int off = 1; off < 64; off <<= 1) m = fmaxf(m, __shfl_xor(m, off));
    __shared__ float sm[5], ssum[5];
    int wv = tid >> 6;
    if ((tid & 63) == 0) sm[wv] = m;
    __syncthreads();
    m = fmaxf(fmaxf(fmaxf(sm[0], sm[1]), fmaxf(sm[2], sm[3])), sm[4]);
    float s = 0.f;
#pragma unroll
    for (int j = 0; j < 25; ++j)
        s += (__expf((float)v[j][0] - m) + __expf((float)v[j][1] - m)) +
             (__expf((float)v[j][2] - m) + __expf((float)v[j][3] - m));
#pragma unroll
    for (int off = 1; off < 64; off <<= 1) s += __shfl_xor(s, off);
    if ((tid & 63) == 0) ssum[wv] = s;
    __syncthreads();
    s = (ssum[0] + ssum[1]) + (ssum[2] + ssum[3]) + ssum[4];
    float lse = m + __logf(s);
#pragma unroll
    for (int j = 0; j < 25; ++j) {
        f32x4 o = {(float)v[j][0] - lse, (float)v[j][1] - lse,
                   (float)v[j][2] - lse, (float)v[j][3] - lse};
        ((f32x4*)orow)[tid + 320 * j] = o;
    }
}

// ---------------- launch ----------------
extern "C" void kernel_launch(void* const* d_in, const int* in_sizes, int n_in,
                              void* d_out, int out_size, void* d_ws, size_t ws_size,
                              hipStream_t stream) {
    const int*   tok   = (const int*)d_in[0];
    const float* emb   = (const float*)d_in[1];
    const float* W_ih1 = (const float*)d_in[2];
    const float* W_hh1 = (const float*)d_in[3];
    const float* b_ih1 = (const float*)d_in[4];
    const float* b_hh1 = (const float*)d_in[5];
    const float* W_ih2 = (const float*)d_in[6];
    const float* W_hh2 = (const float*)d_in[7];
    const float* b_ih2 = (const float*)d_in[8];
    const float* b_hh2 = (const float*)d_in[9];
    const float* W_log = (const float*)d_in[10];
    const float* b_log = (const float*)d_in[11];
    float* out = (float*)d_out;

    char* w = (char*)d_ws;
    auto alloc = [&](size_t bytes) {
        char* p = w;
        w += (bytes + 255) & ~(size_t)255;
        return p;
    };
    _Float16* Wih1h = (_Float16*)alloc((size_t)4096 * 512 * 2);
    _Float16* Whh1h = (_Float16*)alloc((size_t)4096 * 1024 * 2);
    _Float16* Wih2h = (_Float16*)alloc((size_t)4096 * 1024 * 2);
    _Float16* Whh2h = (_Float16*)alloc((size_t)4096 * 1024 * 2);
    _Float16* Wlogh = (_Float16*)alloc((size_t)VOC * 1024 * 2);
    _Float16* Abuf  = (_Float16*)alloc((size_t)4096 * 512 * 2);
    _Float16* Xh    = (_Float16*)alloc((size_t)4096 * 4096 * 2);
    _Float16* h2seq = (_Float16*)alloc((size_t)4096 * 1024 * 2);
    float* b1s      = (float*)alloc(4096 * 4);
    float* b2s      = (float*)alloc(4096 * 4);
    char* h1buf     = alloc(NS * SLOTB);    // 256 KB tag-chunk quad buffer
    char* h2buf     = alloc(NS * SLOTB);    // 256 KB
    unsigned* prog  = (unsigned*)alloc(128 * 64);   // 8 KB progress flags
    // optional f16 logits scratch (262 MB) if workspace allows
    size_t need = (size_t)(w - (char*)d_ws) + (size_t)NROW * VOC * 2;
    _Float16* logh = (need <= ws_size) ? (_Float16*)alloc((size_t)NROW * VOC * 2) : nullptr;

    // zero tag-chunk buffers + progress (tags=0 => "h(-1) published", data=0)
    k_zero<<<64, 256, 0, stream>>>((float*)h1buf, (2 * NS * SLOTB + 128 * 64) / 4);

    // all weight conversions f32 -> f16 in one dispatch (idempotent)
    k_cvt_all<<<2048, 256, 0, stream>>>(W_ih1, W_hh1, W_ih2, W_hh2, W_log,
                                        Wih1h, Whh1h, Wih2h, Whh2h, Wlogh);
    k_bias<<<16, 256, 0, stream>>>(b_ih1, b_hh1, b_ih2, b_hh2, b1s, b2s);

    // X1 = embed @ W_ih1^T + (b_ih1 + b_hh1), f16 out (256x256 pipelined)
    k_embed<<<2048, 256, 0, stream>>>(tok, emb, Abuf);
    k_gemm8<1><<<dim3(16, 16), 512, 0, stream>>>(Abuf, Wih1h, b1s, nullptr, Xh,
                                                 4096, 4096, 512, 0);

    // decoupled 2-layer recurrence (persistent, 128 blocks, tag-in-data)
    k_rnn<<<128, 256, 0, stream>>>(Xh, Whh1h, Wih2h, Whh2h, b2s,
                                   h1buf, h2buf, prog, h2seq);

    // logits = h2_seq @ W_log^T + b_log (256x256 pipelined), then log-softmax
    if (logh) {
        k_gemm8<1><<<dim3(VOC / 256, 16), 512, 0, stream>>>(h2seq, Wlogh, b_log,
                                                            nullptr, logh,
                                                            4096, VOC, 1024, 1);
        k_lsm_h<<<4096, 320, 0, stream>>>(logh, out);
    } else {
        k_gemm8<0><<<dim3(VOC / 256, 16), 512, 0, stream>>>(h2seq, Wlogh, b_log,
                                                            out, nullptr,
                                                            4096, VOC, 1024, 1);
        k_lsm_f<<<4096, 320, 0, stream>>>(out);
    }
}

// Round 14
// 1532.075 us; speedup vs baseline: 1.1164x; 1.1164x over previous
//
#include <hip/hip_runtime.h>
#include <hip/hip_bf16.h>

typedef __attribute__((ext_vector_type(8))) _Float16 half8;
typedef __attribute__((ext_vector_type(4))) _Float16 half4;
typedef __attribute__((ext_vector_type(4))) float f32x4;
typedef __attribute__((ext_vector_type(4))) unsigned int u32x4;

#define VOC 32000
#define EMB 512
#define HID 1024
#define SS  256
#define NROW 4096   // S*B rows, ordered r = t*16 + b
#define CHK 43      // 16B chunks per producer block (6 halves + u32 tag each)
#define CSTRIDE 64  // chunk slots per producer (stride)
#define SLOTB (64 * CSTRIDE * 16)   // bytes per slot = 65536
#define NS 4        // slots per h buffer (quad buffer: WAR slack 3)
#define SPIN (1 << 16)
#define ROWH 264    // LDS halves per producer row (512B data + 16B pad)
// fused in-shadow logits GEMM split
#define SH_TR 30    // row-tiles (128) covered in-shadow: rows < 3840
#define SH_TC 150   // col-tiles (128) covered in-shadow: cols < 19200

__device__ __forceinline__ float sigf(float x) {
    return 1.f / (1.f + __expf(-x));
}
__device__ __forceinline__ float tanh_c(float x) {
    x = fminf(fmaxf(x, -15.f), 15.f);
    float e = __expf(2.f * x);
    return (e - 1.f) / (e + 1.f);
}

// ---- MALL-coherent primitives (bypass L1+L2) ----
__device__ __forceinline__ u32x4 ldg_u4_cc(const void* p) {   // issue only, no wait
    u32x4 r;
    asm volatile("global_load_dwordx4 %0, %1, off sc0 sc1" : "=v"(r) : "v"(p));
    return r;
}
__device__ __forceinline__ void stg_u4_cc(void* p, u32x4 v) {
    asm volatile("global_store_dwordx4 %0, %1, off sc0 sc1" :: "v"(p), "v"(v) : "memory");
}
__device__ __forceinline__ void stg_h8_cc(_Float16* p, half8 v) {
    asm volatile("global_store_dwordx4 %0, %1, off sc0 sc1" :: "v"(p), "v"(v) : "memory");
}
__device__ __forceinline__ void stg_u32_cc(unsigned* p, unsigned v) {
    asm volatile("global_store_dword %0, %1, off sc0 sc1" :: "v"(p), "v"(v) : "memory");
}
__device__ __forceinline__ unsigned ldg_u32_cc(const unsigned* p) {
    unsigned v;
    asm volatile("global_load_dword %0, %1, off sc0 sc1\n\ts_waitcnt vmcnt(0)"
                 : "=v"(v) : "v"(p) : "memory");
    return v;
}
// force a weight fragment into the AGPR file
__device__ __forceinline__ half8 to_agpr(half8 v) {
    asm volatile("" : "+a"(v));
    return v;
}
// async global->LDS, 16B per lane; lds base must be wave-uniform + lane*16
__device__ __forceinline__ void gload16(const void* g, void* lds) {
    __builtin_amdgcn_global_load_lds(
        (const __attribute__((address_space(1))) unsigned int*)(uintptr_t)g,
        (__attribute__((address_space(3))) unsigned int*)(unsigned int)(uintptr_t)lds,
        16, 0, 0);
}

// ---------------- utility kernels ----------------
__global__ void k_zero(float* p, int n) {
    int i = blockIdx.x * blockDim.x + threadIdx.x;
    int st = gridDim.x * blockDim.x;
    for (; i < n; i += st) p[i] = 0.f;
}

// all five weight conversions fused into one grid-stride kernel
__global__ void k_cvt_all(const float* __restrict__ s0, const float* __restrict__ s1,
                          const float* __restrict__ s2, const float* __restrict__ s3,
                          const float* __restrict__ s4,
                          _Float16* __restrict__ d0, _Float16* __restrict__ d1,
                          _Float16* __restrict__ d2, _Float16* __restrict__ d3,
                          _Float16* __restrict__ d4) {
    const int n0 = 4096 * 512 / 4;
    const int n1 = 4096 * 1024 / 4;
    const int n4 = VOC * 1024 / 4;
    const int nT = n0 + 3 * n1 + n4;
    int i = blockIdx.x * 256 + threadIdx.x;
    int st = gridDim.x * 256;
    for (; i < nT; i += st) {
        const float* s; _Float16* d; int k = i;
        if (k < n0) { s = s0; d = d0; }
        else {
            k -= n0;
            if (k < n1) { s = s1; d = d1; }
            else {
                k -= n1;
                if (k < n1) { s = s2; d = d2; }
                else {
                    k -= n1;
                    if (k < n1) { s = s3; d = d3; }
                    else { k -= n1; s = s4; d = d4; }
                }
            }
        }
        float4 v = ((const float4*)s)[k];
        half4 o = {(_Float16)v.x, (_Float16)v.y, (_Float16)v.z, (_Float16)v.w};
        ((half4*)d)[k] = o;
    }
}

__global__ void k_bias(const float* bi1, const float* bh1,
                       const float* bi2, const float* bh2,
                       float* b1, float* b2) {
    int i = blockIdx.x * blockDim.x + threadIdx.x;
    if (i < 4 * HID) { b1[i] = bi1[i] + bh1[i]; b2[i] = bi2[i] + bh2[i]; }
}

// gather embedding rows -> f16 A [4096][512], row r = t*16+b
__global__ void k_embed(const int* __restrict__ tok, const float* __restrict__ emb,
                        _Float16* __restrict__ A) {
    int idx = blockIdx.x * 256 + threadIdx.x;
    if (idx >= NROW * (EMB / 4)) return;
    int r = idx >> 7, c4 = idx & 127;
    int t = r >> 4, b = r & 15;
    int token = tok[b * SS + t];
    float4 v = ((const float4*)(emb + (size_t)token * EMB))[c4];
    half4 o = {(_Float16)v.x, (_Float16)v.y, (_Float16)v.z, (_Float16)v.w};
    ((half4*)(A + (size_t)r * EMB))[c4] = o;
}

// ---------------- 256x256 / BK=64 pipelined GEMM (proven r12) ----------------
template <int F16OUT>
__global__ __launch_bounds__(512, 1) void k_gemm8(
    const _Float16* __restrict__ A, const _Float16* __restrict__ B,
    const float* __restrict__ bias, float* __restrict__ Cf,
    _Float16* __restrict__ Ch, int M, int N, int K, int scatter,
    int rowOff, int colOff) {
    __shared__ __align__(16) char smem[131072];
    int tid = threadIdx.x;
    int wave = tid >> 6, lane = tid & 63;
    int wm = wave >> 2, wn = wave & 3;
    int nbx = gridDim.x;
    int lin = blockIdx.y * nbx + blockIdx.x;
    {   // bijective XCD swizzle when grid % 8 == 0
        int n = nbx * gridDim.y;
        if ((n & 7) == 0) { int cpx = n >> 3; lin = (lin & 7) * cpx + (lin >> 3); }
    }
    int bRow = rowOff + (lin / nbx) * 256, bCol = colOff + (lin % nbx) * 256;
    int nt = K >> 6;
    int lrow = lane & 15, kq = lane >> 4;

    auto stage = [&](int mat, int h, int t) {
        const _Float16* src = mat ? B : A;
        int r0 = mat ? bCol : bRow;
        char* dst = smem + (size_t)(t & 1) * 65536 + mat * 32768 + h * 16384;
#pragma unroll
        for (int j = 0; j < 2; ++j) {
            int ci = j * 512 + tid;
            int row = ci >> 3, slot = ci & 7;
            int grow = h * 128 + row;
            int gsl = slot ^ (row & 7);
            gload16(src + (size_t)(r0 + grow) * K + t * 64 + gsl * 8, dst + ci * 16);
        }
    };
    auto rdA = [&](int bf, int mi, int kk) -> half8 {
        int r = wm * 128 + mi * 16 + lrow;
        int sl = (kk * 4 + kq) ^ (lrow & 7);
        return *(const half8*)(smem + (size_t)bf * 65536 + r * 128 + sl * 16);
    };
    auto rdB = [&](int bf, int ni, int kk) -> half8 {
        int r = wn * 64 + ni * 16 + lrow;
        int sl = (kk * 4 + kq) ^ (lrow & 7);
        return *(const half8*)(smem + (size_t)bf * 65536 + 32768 + r * 128 + sl * 16);
    };

    f32x4 acc[8][4] = {};

    stage(1, 0, 0); stage(0, 0, 0); stage(1, 1, 0); stage(0, 1, 0);
    if (nt > 1) { stage(1, 0, 1); stage(0, 0, 1); }

    for (int u = 0; u < nt; ++u) {
        int bf = u & 1;
        if (u + 1 == nt) asm volatile("s_waitcnt vmcnt(0)" ::: "memory");
        else             asm volatile("s_waitcnt vmcnt(4)" ::: "memory");
        __builtin_amdgcn_s_barrier();
        __builtin_amdgcn_sched_barrier(0);
        if (u + 1 < nt) stage(1, 1, u + 1);
        half8 a[8][2], b[4][2];
#pragma unroll
        for (int mi = 0; mi < 8; ++mi)
#pragma unroll
            for (int kk = 0; kk < 2; ++kk)
                a[mi][kk] = rdA(bf, mi, kk);
#pragma unroll
        for (int ni = 0; ni < 4; ++ni)
#pragma unroll
            for (int kk = 0; kk < 2; ++kk)
                b[ni][kk] = rdB(bf, ni, kk);
        __builtin_amdgcn_s_setprio(1);
#pragma unroll
        for (int mi = 0; mi < 8; ++mi)
#pragma unroll
            for (int ni = 0; ni < 4; ++ni) {
                acc[mi][ni] = __builtin_amdgcn_mfma_f32_16x16x32_f16(a[mi][0], b[ni][0], acc[mi][ni], 0, 0, 0);
                acc[mi][ni] = __builtin_amdgcn_mfma_f32_16x16x32_f16(a[mi][1], b[ni][1], acc[mi][ni], 0, 0, 0);
            }
        __builtin_amdgcn_s_setprio(0);
        asm volatile("s_waitcnt lgkmcnt(0)" ::: "memory");
        __builtin_amdgcn_s_barrier();
        __builtin_amdgcn_sched_barrier(0);
        if (u + 1 < nt) stage(0, 1, u + 1);
        if (u + 2 < nt) { stage(1, 0, u + 2); stage(0, 0, u + 2); }
    }

    float bv[4];
#pragma unroll
    for (int ni = 0; ni < 4; ++ni)
        bv[ni] = bias[bCol + wn * 64 + ni * 16 + lrow];
#pragma unroll
    for (int mi = 0; mi < 8; ++mi)
#pragma unroll
        for (int ni = 0; ni < 4; ++ni)
#pragma unroll
            for (int q = 0; q < 4; ++q) {
                int gr = bRow + wm * 128 + mi * 16 + kq * 4 + q;
                int gc = bCol + wn * 64 + ni * 16 + lrow;
                float v = acc[mi][ni][q] + bv[ni];
                size_t orow = scatter ? (size_t)(((gr & 15) << 8) | (gr >> 4)) : (size_t)gr;
                if (F16OUT) Ch[orow * (size_t)N + gc] = (_Float16)v;
                else        Cf[orow * (size_t)N + gc] = v;
            }
}

// ---------------- tag poll + vectorized LDS stage (round-10 proven) ----------------
__device__ __forceinline__ void poll_stage2(const char* base, int exp, int cnt,
                                            unsigned short* hs, int sbp, int r) {
    u32x4 cv[11];
#pragma unroll
    for (int j = 0; j < 11; ++j)
        if (j < cnt) cv[j] = ldg_u4_cc(base + j * 64);
    for (int it = 0; it < SPIN; ++it) {
        asm volatile("s_waitcnt vmcnt(0)" ::: "memory");
        __builtin_amdgcn_sched_barrier(0);
        bool bad = false;
#pragma unroll
        for (int j = 0; j < 11; ++j)
            if (j < cnt && (int)cv[j][3] < exp) {
                cv[j] = ldg_u4_cc(base + j * 64);
                bad = true;
            }
        if (!bad) break;
        __builtin_amdgcn_s_sleep(1);
    }
#pragma unroll
    for (int j = 0; j < 11; ++j)
        if (j < cnt) {
            int c = r + 4 * j;
            unsigned* dst = (unsigned*)((char*)hs + sbp * (2 * ROWH) + c * 12);
            dst[0] = cv[j][0]; dst[1] = cv[j][1]; dst[2] = cv[j][2];
        }
}

// ---------------- fused kernel: rnn (blocks 0-127) + in-shadow logits GEMM ----------
// rnn: round-10/12 proven structure exactly; h2seq stores now sc0/sc1 (MALL-
// visible mid-kernel). GEMM blocks (128-255) grid-stride 128x128 logits tiles
// (rows < 3840, cols < 19200), each row-tile gated on L2 cohort progress
// prog >= tr*8+12 (row tr*8+7 complete + 3-step visibility slack). One-way
// dependency (gemm waits on rnn) + bounded spins => deadlock-free.
__global__ __launch_bounds__(256, 1) void k_fused(
    const _Float16* __restrict__ X,          // [4096][4096] f16: x1@Wih1^T + b1
    const _Float16* __restrict__ Whh1, const _Float16* __restrict__ Wih2,
    const _Float16* __restrict__ Whh2, const float* __restrict__ b2s,
    char* __restrict__ h1buf, char* __restrict__ h2buf,
    unsigned* __restrict__ prog, _Float16* __restrict__ h2seq,
    const _Float16* __restrict__ Wlog, const float* __restrict__ blog,
    _Float16* __restrict__ logh) {
    __shared__ __align__(16) char smem[84992];   // >80KB: forces 1 block/CU
    int tid = threadIdx.x;
    int bid = blockIdx.x;

    if (bid >= 128) {
        // ============ in-shadow logits GEMM (128x128 tiles, 2-phase) ============
        _Float16* As = (_Float16*)smem;
        _Float16* Bs = (_Float16*)(smem + 8192);
        int wave = tid >> 6, lane = tid & 63;
        int wr = (wave >> 1) * 64, wc = (wave & 1) * 64;
        int lrow = lane & 15, khalf = (lane >> 4) * 8;
        int lcol = lane & 15, lrow4 = (lane >> 4) * 4;
        int pcg = -1;
        for (int idx = bid - 128; idx < SH_TR * SH_TC; idx += 128) {
            int tr = idx / SH_TC, tc = idx % SH_TC;
            int needed = tr * 8 + 12;
            if (pcg < needed) {
                if (tid < 64) {
                    const unsigned* pp = prog + (size_t)(64 + tid) * 16;
                    for (int it = 0; it < SPIN; ++it) {
                        unsigned v = ldg_u32_cc(pp);
                        if ((int)v >= needed) break;
                        __builtin_amdgcn_s_sleep(16);
                    }
                }
                __syncthreads();
                pcg = needed;
            }
            int bRow = tr * 128, bCol = tc * 128;
            f32x4 acc[4][4] = {};
            for (int kt = 0; kt < HID; kt += 32) {
#pragma unroll
                for (int q = 0; q < 2; ++q) {
                    int ci = q * 256 + wave * 64 + lane;
                    int row = ci >> 2, c8 = (ci & 3) * 8;
                    int ldsoff = (q * 256 + wave * 64) * 16;
                    gload16(h2seq + (size_t)(bRow + row) * HID + kt + c8, (char*)As + ldsoff);
                    gload16(Wlog + (size_t)(bCol + row) * HID + kt + c8, (char*)Bs + ldsoff);
                }
                __syncthreads();
                half8 a[4], b[4];
#pragma unroll
                for (int i = 0; i < 4; ++i)
                    a[i] = *(const half8*)(&As[(wr + 16 * i + lrow) * 32 + khalf]);
#pragma unroll
                for (int j = 0; j < 4; ++j)
                    b[j] = *(const half8*)(&Bs[(wc + 16 * j + lrow) * 32 + khalf]);
#pragma unroll
                for (int i = 0; i < 4; ++i)
#pragma unroll
                    for (int j = 0; j < 4; ++j)
                        acc[i][j] = __builtin_amdgcn_mfma_f32_16x16x32_f16(a[i], b[j], acc[i][j], 0, 0, 0);
                __syncthreads();
            }
#pragma unroll
            for (int i = 0; i < 4; ++i)
#pragma unroll
                for (int j = 0; j < 4; ++j)
#pragma unroll
                    for (int q = 0; q < 4; ++q) {
                        int gr = bRow + wr + 16 * i + lrow4 + q;
                        int gc = bCol + wc + 16 * j + lcol;
                        size_t orow = (size_t)(((gr & 15) << 8) | (gr >> 4));
                        logh[orow * (size_t)VOC + gc] = (_Float16)(acc[i][j][q] + blog[gc]);
                    }
        }
        return;
    }

    // ================= rnn (round-10/12 proven structure) =================
    unsigned short* hsPA = (unsigned short*)smem;                 // 33792 B
    unsigned short* hsPB = (unsigned short*)(smem + 33792);       // 33792 B
    float* gsp = (float*)(smem + 67584);                          // 16384 B
    unsigned short* hstage = (unsigned short*)(smem + 83968);     // 528 B
    int w = tid >> 6, l = tid & 63;
    int layer = bid >> 6, sb = bid & 63;
    int sbp = tid >> 2, r = tid & 3;
    int cnt = (r == 3) ? 10 : 11;
    size_t choff = (size_t)(sbp * CSTRIDE + r) * 16;
    int hp = l >> 5;
    int hoff = (l & 15) * 16 + ((l >> 4) & 1) * 8;

    half8 wA[32];   // L1: Whh1 ; L2: Wih2
    half8 wB[32];   // L2: Whh2
    {
        const _Float16* base = layer ? Wih2 : Whh1;
        const _Float16* wp = base + (size_t)(w * HID + sb * 16 + (l & 15)) * HID + (l >> 4) * 8;
#pragma unroll
        for (int kt = 0; kt < 32; ++kt)
            wA[kt] = to_agpr(*(const half8*)(wp + kt * 32));
        if (layer) {
            const _Float16* wq = Whh2 + (size_t)(w * HID + sb * 16 + (l & 15)) * HID + (l >> 4) * 8;
#pragma unroll
            for (int kt = 0; kt < 32; ++kt)
                wB[kt] = to_agpr(*(const half8*)(wq + kt * 32));
        }
    }
    float bias_v = layer ? b2s[w * HID + sb * 16 + (l & 15)] : 0.f;

    int eb = tid >> 4, ecol = tid & 15;
    int gidx = ((eb >> 2) * 16 + ecol) * 4 + (eb & 3);
    float creg = 0.f;
    int pc = 0;

    if (!layer) {
        const _Float16* xbase = X + (size_t)w * HID + sb * 16 + (l & 15);
        int bq = (l >> 4) * 4;
        f32x4 xreg;
        {
            const _Float16* xp = xbase + (size_t)bq * 4096;
            xreg[0] = (float)xp[0]; xreg[1] = (float)xp[4096];
            xreg[2] = (float)xp[8192]; xreg[3] = (float)xp[12288];
        }
        for (int g = 0; g < SS; ++g) {
            int tn = (g + 1 < SS) ? g + 1 : SS - 1;
            const _Float16* xp = xbase + (size_t)(tn * 16 + bq) * 4096;
            float xn0 = (float)xp[0], xn1 = (float)xp[4096],
                  xn2 = (float)xp[8192], xn3 = (float)xp[12288];

            poll_stage2(h1buf + ((g - 1) & 3) * SLOTB + choff, g, cnt, hsPA, sbp, r);
            __syncthreads();
            if (tid == 0) stg_u32_cc(prog + (size_t)bid * 16, (unsigned)(g + 1));

            f32x4 a0 = xreg, a1 = {}, a2 = {}, a3 = {};
#pragma unroll
            for (int c = 0; c < 4; ++c) {
                half8 ha[8];
#pragma unroll
                for (int j = 0; j < 8; ++j)
                    ha[j] = *(const half8*)(hsPA + (2 * (c * 8 + j) + hp) * ROWH + hoff);
#pragma unroll
                for (int j = 0; j < 8; ++j) {
                    f32x4* ac = (j & 3) == 0 ? &a0 : (j & 3) == 1 ? &a1 : (j & 3) == 2 ? &a2 : &a3;
                    *ac = __builtin_amdgcn_mfma_f32_16x16x32_f16(ha[j], wA[c * 8 + j], *ac, 0, 0, 0);
                }
            }
            a0 = (a0 + a1) + (a2 + a3);

            *(f32x4*)(&gsp[w * 1024 + l * 4]) = a0;
            __syncthreads();

            float gi = gsp[gidx], gf = gsp[1024 + gidx],
                  gg = gsp[2048 + gidx], go = gsp[3072 + gidx];
            float cn = sigf(gf) * creg + sigf(gi) * tanh_c(gg);
            float hn = sigf(go) * tanh_c(cn);
            creg = cn;
            _Float16 hh = (_Float16)hn;
            unsigned short hu;
            __builtin_memcpy(&hu, &hh, 2);
            hstage[eb * 16 + ecol] = hu;
            xreg[0] = xn0; xreg[1] = xn1; xreg[2] = xn2; xreg[3] = xn3;
            __syncthreads();

            if (tid < 128 && pc < g - 2) {
                const unsigned* pp = prog + (size_t)tid * 16;
                for (int it = 0; it < SPIN; ++it) {
                    unsigned v = ldg_u32_cc(pp);
                    if ((int)v >= g - 2) { pc = (int)v; break; }
                    __builtin_amdgcn_s_sleep(1);
                }
            }
            __syncthreads();
            if (w == 0 && l < CHK) {
                const unsigned* hsu = (const unsigned*)hstage;
                u32x4 pv;
                pv[0] = hsu[l * 3]; pv[1] = hsu[l * 3 + 1]; pv[2] = hsu[l * 3 + 2];
                pv[3] = (unsigned)(g + 1);
                stg_u4_cc(h1buf + (g & 3) * SLOTB + (size_t)(sb * CSTRIDE + l) * 16, pv);
            }
        }
    } else {
        for (int s = 0; s < SS; ++s) {
            poll_stage2(h2buf + ((s - 1) & 3) * SLOTB + choff, s, cnt, hsPB, sbp, r);
            poll_stage2(h1buf + (s & 3) * SLOTB + choff, s + 1, cnt, hsPA, sbp, r);
            __syncthreads();
            if (tid == 0) stg_u32_cc(prog + (size_t)bid * 16, (unsigned)(s + 1));

            f32x4 a0 = {bias_v, bias_v, bias_v, bias_v}, a1 = {}, a2 = {}, a3 = {};
#pragma unroll
            for (int c = 0; c < 4; ++c) {
                half8 ha[8];
#pragma unroll
                for (int j = 0; j < 8; ++j)
                    ha[j] = *(const half8*)(hsPB + (2 * (c * 8 + j) + hp) * ROWH + hoff);
#pragma unroll
                for (int j = 0; j < 8; ++j) {
                    f32x4* ac = (j & 3) == 0 ? &a0 : (j & 3) == 1 ? &a1 : (j & 3) == 2 ? &a2 : &a3;
                    *ac = __builtin_amdgcn_mfma_f32_16x16x32_f16(ha[j], wB[c * 8 + j], *ac, 0, 0, 0);
                }
            }
#pragma unroll
            for (int c = 0; c < 4; ++c) {
                half8 ha[8];
#pragma unroll
                for (int j = 0; j < 8; ++j)
                    ha[j] = *(const half8*)(hsPA + (2 * (c * 8 + j) + hp) * ROWH + hoff);
#pragma unroll
                for (int j = 0; j < 8; ++j) {
                    f32x4* ac = (j & 3) == 0 ? &a0 : (j & 3) == 1 ? &a1 : (j & 3) == 2 ? &a2 : &a3;
                    *ac = __builtin_amdgcn_mfma_f32_16x16x32_f16(ha[j], wA[c * 8 + j], *ac, 0, 0, 0);
                }
            }
            a0 = (a0 + a1) + (a2 + a3);

            *(f32x4*)(&gsp[w * 1024 + l * 4]) = a0;
            __syncthreads();

            float gi = gsp[gidx], gf = gsp[1024 + gidx],
                  gg = gsp[2048 + gidx], go = gsp[3072 + gidx];
            float cn = sigf(gf) * creg + sigf(gi) * tanh_c(gg);
            float hn = sigf(go) * tanh_c(cn);
            creg = cn;
            _Float16 hh = (_Float16)hn;
            unsigned short hu;
            __builtin_memcpy(&hu, &hh, 2);
            hstage[eb * 16 + ecol] = hu;
            __syncthreads();

            if (tid < 64 && pc < s - 2) {
                const unsigned* pp = prog + (size_t)(64 + tid) * 16;
                for (int it = 0; it < SPIN; ++it) {
                    unsigned v = ldg_u32_cc(pp);
                    if ((int)v >= s - 2) { pc = (int)v; break; }
                    __builtin_amdgcn_s_sleep(1);
                }
            }
            __syncthreads();
            if (w == 0 && l < CHK) {
                const unsigned* hsu = (const unsigned*)hstage;
                u32x4 pv;
                pv[0] = hsu[l * 3]; pv[1] = hsu[l * 3 + 1]; pv[2] = hsu[l * 3 + 2];
                pv[3] = (unsigned)(s + 1);
                stg_u4_cc(h2buf + (s & 3) * SLOTB + (size_t)(sb * CSTRIDE + l) * 16, pv);
            }
            // h2seq row s: sc0/sc1 write-through -> MALL-visible for gemm blocks
            if (w == 1 && l < 32) {
                half8 hv = *(const half8*)((const char*)hstage + l * 16);
                stg_h8_cc(h2seq + (size_t)(s * 16 + (l >> 1)) * HID + sb * 16 + (l & 1) * 8, hv);
            }
        }
    }
}

// ---------------- fused log-softmax, f32 in-place ----------------
__global__ __launch_bounds__(320) void k_lsm_f(float* __restrict__ logits) {
    int r = blockIdx.x, tid = threadIdx.x;
    float* row = logits + (size_t)r * VOC;
    f32x4 v[25];
    float m = -3.4e38f;
#pragma unroll
    for (int j = 0; j < 25; ++j) {
        v[j] = ((const f32x4*)row)[tid + 320 * j];
        m = fmaxf(fmaxf(fmaxf(m, v[j][0]), fmaxf(v[j][1], v[j][2])), v[j][3]);
    }
#pragma unroll
    for (int off = 1; off < 64; off <<= 1) m = fmaxf(m, __shfl_xor(m, off));
    __shared__ float sm[5], ssum[5];
    int wv = tid >> 6;
    if ((tid & 63) == 0) sm[wv] = m;
    __syncthreads();
    m = fmaxf(fmaxf(fmaxf(sm[0], sm[1]), fmaxf(sm[2], sm[3])), sm[4]);
    float s = 0.f;
#pragma unroll
    for (int j = 0; j < 25; ++j)
        s += (__expf(v[j][0] - m) + __expf(v[j][1] - m)) +
             (__expf(v[j][2] - m) + __expf(v[j][3] - m));
#pragma unroll
    for (int off = 1; off < 64; off <<= 1) s += __shfl_xor(s, off);
    if ((tid & 63) == 0) ssum[wv] = s;
    __syncthreads();
    s = (ssum[0] + ssum[1]) + (ssum[2] + ssum[3]) + ssum[4];
    float lse = m + __logf(s);
#pragma unroll
    for (int j = 0; j < 25; ++j) {
        f32x4 o = v[j];
        o[0] -= lse; o[1] -= lse; o[2] -= lse; o[3] -= lse;
        ((f32x4*)row)[tid + 320 * j] = o;
    }
}

// ---------------- fused log-softmax, f16 in -> f32 out ----------------
__global__ __launch_bounds__(320) void k_lsm_h(const _Float16* __restrict__ lg,
                                               float* __restrict__ out) {
    int r = blockIdx.x, tid = threadIdx.x;
    const half4* row = (const half4*)(lg + (size_t)r * VOC);
    float* orow = out + (size_t)r * VOC;
    half4 v[25];
    float m = -3.4e38f;
#pragma unroll
    for (int j = 0; j < 25; ++j) {
        v[j] = row[tid + 320 * j];
        float a = (float)v[j][0], b = (float)v[j][1], c = (float)v[j][2], d = (float)v[j][3];
        m = fmaxf(fmaxf(fmaxf(m, a), fmaxf(b, c)), d);
    }
#pragma unroll
    for (int off = 1; off < 64; off <<= 1) m = fmaxf(m, __shfl_xor(m, off));
    __shared__ float sm[5], ssum[5];
    int wv = tid >> 6;
    if ((tid & 63) == 0) sm[wv] = m;
    __syncthreads();
    m = fmaxf(fmaxf(fmaxf(sm[0], sm[1]), fmaxf(sm[2], sm[3])), sm[4]);
    float s = 0.f;
#pragma unroll
    for (int j = 0; j < 25; ++j)
        s += (__expf((float)v[j][0] - m) + __expf((float)v[j][1] - m)) +
             (__expf((float)v[j][2] - m) + __expf((float)v[j][3] - m));
#pragma unroll
    for (int off = 1; off < 64; off <<= 1) s += __shfl_xor(s, off);
    if ((tid & 63) == 0) ssum[wv] = s;
    __syncthreads();
    s = (ssum[0] + ssum[1]) + (ssum[2] + ssum[3]) + ssum[4];
    float lse = m + __logf(s);
#pragma unroll
    for (int j = 0; j < 25; ++j) {
        f32x4 o = {(float)v[j][0] - lse, (float)v[j][1] - lse,
                   (float)v[j][2] - lse, (float)v[j][3] - lse};
        ((f32x4*)orow)[tid + 320 * j] = o;
    }
}

// ---------------- launch ----------------
extern "C" void kernel_launch(void* const* d_in, const int* in_sizes, int n_in,
                              void* d_out, int out_size, void* d_ws, size_t ws_size,
                              hipStream_t stream) {
    const int*   tok   = (const int*)d_in[0];
    const float* emb   = (const float*)d_in[1];
    const float* W_ih1 = (const float*)d_in[2];
    const float* W_hh1 = (const float*)d_in[3];
    const float* b_ih1 = (const float*)d_in[4];
    const float* b_hh1 = (const float*)d_in[5];
    const float* W_ih2 = (const float*)d_in[6];
    const float* W_hh2 = (const float*)d_in[7];
    const float* b_ih2 = (const float*)d_in[8];
    const float* b_hh2 = (const float*)d_in[9];
    const float* W_log = (const float*)d_in[10];
    const float* b_log = (const float*)d_in[11];
    float* out = (float*)d_out;

    char* w = (char*)d_ws;
    auto alloc = [&](size_t bytes) {
        char* p = w;
        w += (bytes + 255) & ~(size_t)255;
        return p;
    };
    _Float16* Wih1h = (_Float16*)alloc((size_t)4096 * 512 * 2);
    _Float16* Whh1h = (_Float16*)alloc((size_t)4096 * 1024 * 2);
    _Float16* Wih2h = (_Float16*)alloc((size_t)4096 * 1024 * 2);
    _Float16* Whh2h = (_Float16*)alloc((size_t)4096 * 1024 * 2);
    _Float16* Wlogh = (_Float16*)alloc((size_t)VOC * 1024 * 2);
    _Float16* Abuf  = (_Float16*)alloc((size_t)4096 * 512 * 2);
    _Float16* Xh    = (_Float16*)alloc((size_t)4096 * 4096 * 2);
    _Float16* h2seq = (_Float16*)alloc((size_t)4096 * 1024 * 2);
    float* b1s      = (float*)alloc(4096 * 4);
    float* b2s      = (float*)alloc(4096 * 4);
    char* h1buf     = alloc(NS * SLOTB);    // 256 KB tag-chunk quad buffer
    char* h2buf     = alloc(NS * SLOTB);    // 256 KB
    unsigned* prog  = (unsigned*)alloc(128 * 64);   // 8 KB progress flags
    size_t need = (size_t)(w - (char*)d_ws) + (size_t)NROW * VOC * 2;
    _Float16* logh = (need <= ws_size) ? (_Float16*)alloc((size_t)NROW * VOC * 2) : nullptr;

    // zero tag-chunk buffers + progress (tags=0 => "h(-1) published", data=0)
    k_zero<<<64, 256, 0, stream>>>((float*)h1buf, (2 * NS * SLOTB + 128 * 64) / 4);

    // all weight conversions f32 -> f16 in one dispatch (idempotent)
    k_cvt_all<<<2048, 256, 0, stream>>>(W_ih1, W_hh1, W_ih2, W_hh2, W_log,
                                        Wih1h, Whh1h, Wih2h, Whh2h, Wlogh);
    k_bias<<<16, 256, 0, stream>>>(b_ih1, b_hh1, b_ih2, b_hh2, b1s, b2s);

    // X1 = embed @ W_ih1^T + (b_ih1 + b_hh1), f16 out (256x256 pipelined)
    k_embed<<<2048, 256, 0, stream>>>(tok, emb, Abuf);
    k_gemm8<1><<<dim3(16, 16), 512, 0, stream>>>(Abuf, Wih1h, b1s, nullptr, Xh,
                                                 4096, 4096, 512, 0, 0, 0);

    if (logh) {
        // fused: recurrence (128 blocks) + in-shadow logits GEMM (128 blocks)
        k_fused<<<256, 256, 0, stream>>>(Xh, Whh1h, Wih2h, Whh2h, b2s,
                                         h1buf, h2buf, prog, h2seq,
                                         Wlogh, b_log, logh);
        // tails: cols >= 19200 (all rows); rows >= 3840 (cols < 19200)
        k_gemm8<1><<<dim3(50, 16), 512, 0, stream>>>(h2seq, Wlogh, b_log, nullptr,
                                                     logh, 4096, VOC, 1024, 1,
                                                     0, 19200);
        k_gemm8<1><<<dim3(75, 1), 512, 0, stream>>>(h2seq, Wlogh, b_log, nullptr,
                                                    logh, 4096, VOC, 1024, 1,
                                                    3840, 0);
        k_lsm_h<<<4096, 320, 0, stream>>>(logh, out);
    } else {
        k_fused<<<128, 256, 0, stream>>>(Xh, Whh1h, Wih2h, Whh2h, b2s,
                                         h1buf, h2buf, prog, h2seq,
                                         Wlogh, b_log, nullptr);
        k_gemm8<0><<<dim3(VOC / 256, 16), 512, 0, stream>>>(h2seq, Wlogh, b_log,
                                                            out, nullptr,
                                                            4096, VOC, 1024, 1, 0, 0);
        k_lsm_f<<<4096, 320, 0, stream>>>(out);
    }
}

// Round 15
// 1417.015 us; speedup vs baseline: 1.2071x; 1.0812x over previous
//
#include <hip/hip_runtime.h>
#include <hip/hip_bf16.h>

typedef __attribute__((ext_vector_type(8))) _Float16 half8;
typedef __attribute__((ext_vector_type(4))) _Float16 half4;
typedef __attribute__((ext_vector_type(4))) float f32x4;
typedef __attribute__((ext_vector_type(4))) unsigned int u32x4;

#define VOC 32000
#define EMB 512
#define HID 1024
#define SS  256
#define NROW 4096   // S*B rows, ordered r = t*16 + b
#define CHK 43      // 16B chunks per producer block (6 halves + u32 tag each)
#define CSTRIDE 64  // chunk slots per producer (stride)
#define SLOTB (64 * CSTRIDE * 16)   // bytes per slot = 65536
#define NS 4        // slots per h buffer (quad buffer: WAR slack 3)
#define SPIN (1 << 16)
#define ROWH 264    // LDS halves per producer row (512B data + 16B pad)
#define NTILE (32 * 250)   // 128x128 logits tiles

__device__ __forceinline__ float sigf(float x) {
    return 1.f / (1.f + __expf(-x));
}
__device__ __forceinline__ float tanh_c(float x) {
    x = fminf(fmaxf(x, -15.f), 15.f);
    float e = __expf(2.f * x);
    return (e - 1.f) / (e + 1.f);
}

// ---- MALL-coherent primitives (bypass L1+L2) ----
__device__ __forceinline__ u32x4 ldg_u4_cc(const void* p) {   // issue only, no wait
    u32x4 r;
    asm volatile("global_load_dwordx4 %0, %1, off sc0 sc1" : "=v"(r) : "v"(p));
    return r;
}
__device__ __forceinline__ void stg_u4_cc(void* p, u32x4 v) {
    asm volatile("global_store_dwordx4 %0, %1, off sc0 sc1" :: "v"(p), "v"(v) : "memory");
}
__device__ __forceinline__ void stg_h8_cc(_Float16* p, half8 v) {
    asm volatile("global_store_dwordx4 %0, %1, off sc0 sc1" :: "v"(p), "v"(v) : "memory");
}
__device__ __forceinline__ void stg_u32_cc(unsigned* p, unsigned v) {
    asm volatile("global_store_dword %0, %1, off sc0 sc1" :: "v"(p), "v"(v) : "memory");
}
__device__ __forceinline__ unsigned ldg_u32_cc(const unsigned* p) {
    unsigned v;
    asm volatile("global_load_dword %0, %1, off sc0 sc1\n\ts_waitcnt vmcnt(0)"
                 : "=v"(v) : "v"(p) : "memory");
    return v;
}
// force a weight fragment into the AGPR file
__device__ __forceinline__ half8 to_agpr(half8 v) {
    asm volatile("" : "+a"(v));
    return v;
}
// async global->LDS, 16B per lane; lds base must be wave-uniform + lane*16
__device__ __forceinline__ void gload16(const void* g, void* lds) {
    __builtin_amdgcn_global_load_lds(
        (const __attribute__((address_space(1))) unsigned int*)(uintptr_t)g,
        (__attribute__((address_space(3))) unsigned int*)(unsigned int)(uintptr_t)lds,
        16, 0, 0);
}

// ---------------- utility kernels ----------------
__global__ void k_zero(float* p, int n) {
    int i = blockIdx.x * blockDim.x + threadIdx.x;
    int st = gridDim.x * blockDim.x;
    for (; i < n; i += st) p[i] = 0.f;
}

// all five weight conversions fused into one grid-stride kernel
__global__ void k_cvt_all(const float* __restrict__ s0, const float* __restrict__ s1,
                          const float* __restrict__ s2, const float* __restrict__ s3,
                          const float* __restrict__ s4,
                          _Float16* __restrict__ d0, _Float16* __restrict__ d1,
                          _Float16* __restrict__ d2, _Float16* __restrict__ d3,
                          _Float16* __restrict__ d4) {
    const int n0 = 4096 * 512 / 4;
    const int n1 = 4096 * 1024 / 4;
    const int n4 = VOC * 1024 / 4;
    const int nT = n0 + 3 * n1 + n4;
    int i = blockIdx.x * 256 + threadIdx.x;
    int st = gridDim.x * 256;
    for (; i < nT; i += st) {
        const float* s; _Float16* d; int k = i;
        if (k < n0) { s = s0; d = d0; }
        else {
            k -= n0;
            if (k < n1) { s = s1; d = d1; }
            else {
                k -= n1;
                if (k < n1) { s = s2; d = d2; }
                else {
                    k -= n1;
                    if (k < n1) { s = s3; d = d3; }
                    else { k -= n1; s = s4; d = d4; }
                }
            }
        }
        float4 v = ((const float4*)s)[k];
        half4 o = {(_Float16)v.x, (_Float16)v.y, (_Float16)v.z, (_Float16)v.w};
        ((half4*)d)[k] = o;
    }
}

__global__ void k_bias(const float* bi1, const float* bh1,
                       const float* bi2, const float* bh2,
                       float* b1, float* b2) {
    int i = blockIdx.x * blockDim.x + threadIdx.x;
    if (i < 4 * HID) { b1[i] = bi1[i] + bh1[i]; b2[i] = bi2[i] + bh2[i]; }
}

// gather embedding rows -> f16 A [4096][512], row r = t*16+b
__global__ void k_embed(const int* __restrict__ tok, const float* __restrict__ emb,
                        _Float16* __restrict__ A) {
    int idx = blockIdx.x * 256 + threadIdx.x;
    if (idx >= NROW * (EMB / 4)) return;
    int r = idx >> 7, c4 = idx & 127;
    int t = r >> 4, b = r & 15;
    int token = tok[b * SS + t];
    float4 v = ((const float4*)(emb + (size_t)token * EMB))[c4];
    half4 o = {(_Float16)v.x, (_Float16)v.y, (_Float16)v.z, (_Float16)v.w};
    ((half4*)(A + (size_t)r * EMB))[c4] = o;
}

// ---------------- 256x256 / BK=64 pipelined GEMM (proven r12) ----------------
template <int F16OUT>
__global__ __launch_bounds__(512, 1) void k_gemm8(
    const _Float16* __restrict__ A, const _Float16* __restrict__ B,
    const float* __restrict__ bias, float* __restrict__ Cf,
    _Float16* __restrict__ Ch, int M, int N, int K, int scatter,
    int rowOff, int colOff) {
    __shared__ __align__(16) char smem[131072];
    int tid = threadIdx.x;
    int wave = tid >> 6, lane = tid & 63;
    int wm = wave >> 2, wn = wave & 3;
    int nbx = gridDim.x;
    int lin = blockIdx.y * nbx + blockIdx.x;
    {
        int n = nbx * gridDim.y;
        if ((n & 7) == 0) { int cpx = n >> 3; lin = (lin & 7) * cpx + (lin >> 3); }
    }
    int bRow = rowOff + (lin / nbx) * 256, bCol = colOff + (lin % nbx) * 256;
    int nt = K >> 6;
    int lrow = lane & 15, kq = lane >> 4;

    auto stage = [&](int mat, int h, int t) {
        const _Float16* src = mat ? B : A;
        int r0 = mat ? bCol : bRow;
        char* dst = smem + (size_t)(t & 1) * 65536 + mat * 32768 + h * 16384;
#pragma unroll
        for (int j = 0; j < 2; ++j) {
            int ci = j * 512 + tid;
            int row = ci >> 3, slot = ci & 7;
            int grow = h * 128 + row;
            int gsl = slot ^ (row & 7);
            gload16(src + (size_t)(r0 + grow) * K + t * 64 + gsl * 8, dst + ci * 16);
        }
    };
    auto rdA = [&](int bf, int mi, int kk) -> half8 {
        int r = wm * 128 + mi * 16 + lrow;
        int sl = (kk * 4 + kq) ^ (lrow & 7);
        return *(const half8*)(smem + (size_t)bf * 65536 + r * 128 + sl * 16);
    };
    auto rdB = [&](int bf, int ni, int kk) -> half8 {
        int r = wn * 64 + ni * 16 + lrow;
        int sl = (kk * 4 + kq) ^ (lrow & 7);
        return *(const half8*)(smem + (size_t)bf * 65536 + 32768 + r * 128 + sl * 16);
    };

    f32x4 acc[8][4] = {};

    stage(1, 0, 0); stage(0, 0, 0); stage(1, 1, 0); stage(0, 1, 0);
    if (nt > 1) { stage(1, 0, 1); stage(0, 0, 1); }

    for (int u = 0; u < nt; ++u) {
        int bf = u & 1;
        if (u + 1 == nt) asm volatile("s_waitcnt vmcnt(0)" ::: "memory");
        else             asm volatile("s_waitcnt vmcnt(4)" ::: "memory");
        __builtin_amdgcn_s_barrier();
        __builtin_amdgcn_sched_barrier(0);
        if (u + 1 < nt) stage(1, 1, u + 1);
        half8 a[8][2], b[4][2];
#pragma unroll
        for (int mi = 0; mi < 8; ++mi)
#pragma unroll
            for (int kk = 0; kk < 2; ++kk)
                a[mi][kk] = rdA(bf, mi, kk);
#pragma unroll
        for (int ni = 0; ni < 4; ++ni)
#pragma unroll
            for (int kk = 0; kk < 2; ++kk)
                b[ni][kk] = rdB(bf, ni, kk);
        __builtin_amdgcn_s_setprio(1);
#pragma unroll
        for (int mi = 0; mi < 8; ++mi)
#pragma unroll
            for (int ni = 0; ni < 4; ++ni) {
                acc[mi][ni] = __builtin_amdgcn_mfma_f32_16x16x32_f16(a[mi][0], b[ni][0], acc[mi][ni], 0, 0, 0);
                acc[mi][ni] = __builtin_amdgcn_mfma_f32_16x16x32_f16(a[mi][1], b[ni][1], acc[mi][ni], 0, 0, 0);
            }
        __builtin_amdgcn_s_setprio(0);
        asm volatile("s_waitcnt lgkmcnt(0)" ::: "memory");
        __builtin_amdgcn_s_barrier();
        __builtin_amdgcn_sched_barrier(0);
        if (u + 1 < nt) stage(0, 1, u + 1);
        if (u + 2 < nt) { stage(1, 0, u + 2); stage(0, 0, u + 2); }
    }

    float bv[4];
#pragma unroll
    for (int ni = 0; ni < 4; ++ni)
        bv[ni] = bias[bCol + wn * 64 + ni * 16 + lrow];
#pragma unroll
    for (int mi = 0; mi < 8; ++mi)
#pragma unroll
        for (int ni = 0; ni < 4; ++ni)
#pragma unroll
            for (int q = 0; q < 4; ++q) {
                int gr = bRow + wm * 128 + mi * 16 + kq * 4 + q;
                int gc = bCol + wn * 64 + ni * 16 + lrow;
                float v = acc[mi][ni][q] + bv[ni];
                size_t orow = scatter ? (size_t)(((gr & 15) << 8) | (gr >> 4)) : (size_t)gr;
                if (F16OUT) Ch[orow * (size_t)N + gc] = (_Float16)v;
                else        Cf[orow * (size_t)N + gc] = v;
            }
}

// ---------------- tag poll + vectorized LDS stage (round-10 proven) ----------------
__device__ __forceinline__ void poll_stage2(const char* base, int exp, int cnt,
                                            unsigned short* hs, int sbp, int r) {
    u32x4 cv[11];
#pragma unroll
    for (int j = 0; j < 11; ++j)
        if (j < cnt) cv[j] = ldg_u4_cc(base + j * 64);
    for (int it = 0; it < SPIN; ++it) {
        asm volatile("s_waitcnt vmcnt(0)" ::: "memory");
        __builtin_amdgcn_sched_barrier(0);
        bool bad = false;
#pragma unroll
        for (int j = 0; j < 11; ++j)
            if (j < cnt && (int)cv[j][3] < exp) {
                cv[j] = ldg_u4_cc(base + j * 64);
                bad = true;
            }
        if (!bad) break;
        __builtin_amdgcn_s_sleep(1);
    }
#pragma unroll
    for (int j = 0; j < 11; ++j)
        if (j < cnt) {
            int c = r + 4 * j;
            unsigned* dst = (unsigned*)((char*)hs + sbp * (2 * ROWH) + c * 12);
            dst[0] = cv[j][0]; dst[1] = cv[j][1]; dst[2] = cv[j][2];
        }
}

// ---------------- work-stealing logits GEMM (128x128, dbuf, counted vmcnt) --------
// All participating blocks pull tile indices from wq. Tile idx -> tr=idx/250,
// tc=idx%250. Row gate: prog2[sb] >= tr*8+8 certifies h2seq rows t<=tr*8+7
// are MALL-visible (flags are published only after a per-wave vmcnt drain).
__device__ __forceinline__ void gemm_ws(
    const _Float16* __restrict__ h2seq, const _Float16* __restrict__ Wlog,
    const float* __restrict__ blog, _Float16* __restrict__ logh,
    unsigned* prog2, unsigned* wq, char* smem, int tid) {
    int wave = tid >> 6, lane = tid & 63;
    int wr = (wave >> 1) * 64, wc = (wave & 1) * 64;
    int lrow = lane & 15, kq = lane >> 4;
    int lrow4 = (lane >> 4) * 4;
    volatile int* tsh = (int*)(smem + 84960);
    int pcg = -1;
    for (;;) {
        __syncthreads();                     // protect tsh + LDS buffer reuse
        if (tid == 0) *tsh = (int)atomicAdd(wq, 1u);
        __syncthreads();
        int idx = *tsh;
        if (idx >= NTILE) break;
        int tr = idx / 250, tc = idx - tr * 250;
        int needed = tr * 8 + 8;
        if (pcg < needed) {
            if (tid < 64) {
                const unsigned* pp = prog2 + (size_t)tid * 16;
                for (int it = 0; it < SPIN; ++it) {
                    unsigned v = ldg_u32_cc(pp);
                    if ((int)v >= needed) break;
                    __builtin_amdgcn_s_sleep(16);
                }
            }
            __syncthreads();
            pcg = needed;
        }
        int bRow = tr * 128, bCol = tc * 128;
        // stage K-step u into buffer u&1 (4 gload16/thread, pre-swizzled src)
        auto stage = [&](int u) {
            int bf = u & 1;
#pragma unroll
            for (int j = 0; j < 2; ++j) {
                int ci = j * 256 + tid;
                int row = ci >> 2, sl = ci & 3;
                int gsl = (sl ^ (row & 3)) * 8;
                char* basep = smem + bf * 16384 + (j * 256 + wave * 64) * 16;
                gload16(h2seq + (size_t)(bRow + row) * HID + u * 32 + gsl, basep);
                gload16(Wlog + (size_t)(bCol + row) * HID + u * 32 + gsl,
                        basep + 8192);
            }
        };
        auto rdA = [&](int bf, int i) -> half8 {
            int r = wr + 16 * i + lrow;
            int p = kq ^ (r & 3);
            return *(const half8*)(smem + bf * 16384 + r * 64 + p * 16);
        };
        auto rdB = [&](int bf, int j) -> half8 {
            int r = wc + 16 * j + lrow;
            int p = kq ^ (r & 3);
            return *(const half8*)(smem + bf * 16384 + 8192 + r * 64 + p * 16);
        };
        f32x4 acc[4][4] = {};
        stage(0);
        for (int u = 0; u < 32; ++u) {
            if (u + 1 < 32) {
                stage(u + 1);
                asm volatile("s_waitcnt vmcnt(4)" ::: "memory");
            } else {
                asm volatile("s_waitcnt vmcnt(0)" ::: "memory");
            }
            __builtin_amdgcn_s_barrier();
            __builtin_amdgcn_sched_barrier(0);
            int bf = u & 1;
            half8 a[4], b[4];
#pragma unroll
            for (int i = 0; i < 4; ++i) a[i] = rdA(bf, i);
#pragma unroll
            for (int j = 0; j < 4; ++j) b[j] = rdB(bf, j);
            __builtin_amdgcn_s_setprio(1);
#pragma unroll
            for (int i = 0; i < 4; ++i)
#pragma unroll
                for (int j = 0; j < 4; ++j)
                    acc[i][j] = __builtin_amdgcn_mfma_f32_16x16x32_f16(a[i], b[j], acc[i][j], 0, 0, 0);
            __builtin_amdgcn_s_setprio(0);
            asm volatile("s_waitcnt lgkmcnt(0)" ::: "memory");
            __builtin_amdgcn_s_barrier();
            __builtin_amdgcn_sched_barrier(0);
        }
#pragma unroll
        for (int i = 0; i < 4; ++i)
#pragma unroll
            for (int j = 0; j < 4; ++j)
#pragma unroll
                for (int q = 0; q < 4; ++q) {
                    int gr = bRow + wr + 16 * i + lrow4 + q;
                    int gc = bCol + wc + 16 * j + lrow;
                    size_t orow = (size_t)(((gr & 15) << 8) | (gr >> 4));
                    logh[orow * (size_t)VOC + gc] = (_Float16)(acc[i][j][q] + blog[gc]);
                }
    }
}

// ---------------- fused kernel: rnn (0-127) + work-steal logits GEMM ---------------
__global__ __launch_bounds__(256, 1) void k_fused(
    const _Float16* __restrict__ X,          // [4096][4096] f16: x1@Wih1^T + b1
    const _Float16* __restrict__ Whh1, const _Float16* __restrict__ Wih2,
    const _Float16* __restrict__ Whh2, const float* __restrict__ b2s,
    char* __restrict__ h1buf, char* __restrict__ h2buf,
    unsigned* __restrict__ prog, _Float16* __restrict__ h2seq,
    const _Float16* __restrict__ Wlog, const float* __restrict__ blog,
    _Float16* __restrict__ logh) {
    __shared__ __align__(16) char smem[84992];   // >80KB: 1 block/CU
    int tid = threadIdx.x;
    int bid = blockIdx.x;
    unsigned* prog2 = prog + 2048;   // 64 slots x 64B
    unsigned* wq = prog + 3072;      // work-queue counter

    if (bid >= 128) {
        gemm_ws(h2seq, Wlog, blog, logh, prog2, wq, smem, tid);
        return;
    }

    // ================= rnn (round-10/12 proven structure) =================
    unsigned short* hsPA = (unsigned short*)smem;                 // 33792 B
    unsigned short* hsPB = (unsigned short*)(smem + 33792);       // 33792 B
    float* gsp = (float*)(smem + 67584);                          // 16384 B
    unsigned short* hstage = (unsigned short*)(smem + 83968);     // 528 B
    int w = tid >> 6, l = tid & 63;
    int layer = bid >> 6, sb = bid & 63;
    int sbp = tid >> 2, r = tid & 3;
    int cnt = (r == 3) ? 10 : 11;
    size_t choff = (size_t)(sbp * CSTRIDE + r) * 16;
    int hp = l >> 5;
    int hoff = (l & 15) * 16 + ((l >> 4) & 1) * 8;

    half8 wA[32];   // L1: Whh1 ; L2: Wih2
    half8 wB[32];   // L2: Whh2
    {
        const _Float16* base = layer ? Wih2 : Whh1;
        const _Float16* wp = base + (size_t)(w * HID + sb * 16 + (l & 15)) * HID + (l >> 4) * 8;
#pragma unroll
        for (int kt = 0; kt < 32; ++kt)
            wA[kt] = to_agpr(*(const half8*)(wp + kt * 32));
        if (layer) {
            const _Float16* wq2 = Whh2 + (size_t)(w * HID + sb * 16 + (l & 15)) * HID + (l >> 4) * 8;
#pragma unroll
            for (int kt = 0; kt < 32; ++kt)
                wB[kt] = to_agpr(*(const half8*)(wq2 + kt * 32));
        }
    }
    float bias_v = layer ? b2s[w * HID + sb * 16 + (l & 15)] : 0.f;

    int eb = tid >> 4, ecol = tid & 15;
    int gidx = ((eb >> 2) * 16 + ecol) * 4 + (eb & 3);
    float creg = 0.f;
    int pc = 0;

    if (!layer) {
        const _Float16* xbase = X + (size_t)w * HID + sb * 16 + (l & 15);
        int bq = (l >> 4) * 4;
        f32x4 xreg;
        {
            const _Float16* xp = xbase + (size_t)bq * 4096;
            xreg[0] = (float)xp[0]; xreg[1] = (float)xp[4096];
            xreg[2] = (float)xp[8192]; xreg[3] = (float)xp[12288];
        }
        for (int g = 0; g < SS; ++g) {
            int tn = (g + 1 < SS) ? g + 1 : SS - 1;
            const _Float16* xp = xbase + (size_t)(tn * 16 + bq) * 4096;
            float xn0 = (float)xp[0], xn1 = (float)xp[4096],
                  xn2 = (float)xp[8192], xn3 = (float)xp[12288];

            poll_stage2(h1buf + ((g - 1) & 3) * SLOTB + choff, g, cnt, hsPA, sbp, r);
            __syncthreads();
            if (tid == 0) stg_u32_cc(prog + (size_t)bid * 16, (unsigned)(g + 1));

            f32x4 a0 = xreg, a1 = {}, a2 = {}, a3 = {};
#pragma unroll
            for (int c = 0; c < 4; ++c) {
                half8 ha[8];
#pragma unroll
                for (int j = 0; j < 8; ++j)
                    ha[j] = *(const half8*)(hsPA + (2 * (c * 8 + j) + hp) * ROWH + hoff);
#pragma unroll
                for (int j = 0; j < 8; ++j) {
                    f32x4* ac = (j & 3) == 0 ? &a0 : (j & 3) == 1 ? &a1 : (j & 3) == 2 ? &a2 : &a3;
                    *ac = __builtin_amdgcn_mfma_f32_16x16x32_f16(ha[j], wA[c * 8 + j], *ac, 0, 0, 0);
                }
            }
            a0 = (a0 + a1) + (a2 + a3);

            *(f32x4*)(&gsp[w * 1024 + l * 4]) = a0;
            __syncthreads();

            float gi = gsp[gidx], gf = gsp[1024 + gidx],
                  gg = gsp[2048 + gidx], go = gsp[3072 + gidx];
            float cn = sigf(gf) * creg + sigf(gi) * tanh_c(gg);
            float hn = sigf(go) * tanh_c(cn);
            creg = cn;
            _Float16 hh = (_Float16)hn;
            unsigned short hu;
            __builtin_memcpy(&hu, &hh, 2);
            hstage[eb * 16 + ecol] = hu;
            xreg[0] = xn0; xreg[1] = xn1; xreg[2] = xn2; xreg[3] = xn3;
            __syncthreads();

            if (tid < 128 && pc < g - 2) {
                const unsigned* pp = prog + (size_t)tid * 16;
                for (int it = 0; it < SPIN; ++it) {
                    unsigned v = ldg_u32_cc(pp);
                    if ((int)v >= g - 2) { pc = (int)v; break; }
                    __builtin_amdgcn_s_sleep(1);
                }
            }
            __syncthreads();
            if (w == 0 && l < CHK) {
                const unsigned* hsu = (const unsigned*)hstage;
                u32x4 pv;
                pv[0] = hsu[l * 3]; pv[1] = hsu[l * 3 + 1]; pv[2] = hsu[l * 3 + 2];
                pv[3] = (unsigned)(g + 1);
                stg_u4_cc(h1buf + (g & 3) * SLOTB + (size_t)(sb * CSTRIDE + l) * 16, pv);
            }
        }
    } else {
        for (int s = 0; s < SS; ++s) {
            poll_stage2(h2buf + ((s - 1) & 3) * SLOTB + choff, s, cnt, hsPB, sbp, r);
            poll_stage2(h1buf + (s & 3) * SLOTB + choff, s + 1, cnt, hsPA, sbp, r);
            __syncthreads();
            // all waves drained vmcnt(0) in the polls => step s-1 h2seq stores
            // are MALL-visible; publish exact row progress for the gemm gate.
            if (tid == 0) stg_u32_cc(prog + (size_t)bid * 16, (unsigned)(s + 1));
            if (tid == 1) stg_u32_cc(prog + 2048 + (size_t)sb * 16, (unsigned)s);

            f32x4 a0 = {bias_v, bias_v, bias_v, bias_v}, a1 = {}, a2 = {}, a3 = {};
#pragma unroll
            for (int c = 0; c < 4; ++c) {
                half8 ha[8];
#pragma unroll
                for (int j = 0; j < 8; ++j)
                    ha[j] = *(const half8*)(hsPB + (2 * (c * 8 + j) + hp) * ROWH + hoff);
#pragma unroll
                for (int j = 0; j < 8; ++j) {
                    f32x4* ac = (j & 3) == 0 ? &a0 : (j & 3) == 1 ? &a1 : (j & 3) == 2 ? &a2 : &a3;
                    *ac = __builtin_amdgcn_mfma_f32_16x16x32_f16(ha[j], wB[c * 8 + j], *ac, 0, 0, 0);
                }
            }
#pragma unroll
            for (int c = 0; c < 4; ++c) {
                half8 ha[8];
#pragma unroll
                for (int j = 0; j < 8; ++j)
                    ha[j] = *(const half8*)(hsPA + (2 * (c * 8 + j) + hp) * ROWH + hoff);
#pragma unroll
                for (int j = 0; j < 8; ++j) {
                    f32x4* ac = (j & 3) == 0 ? &a0 : (j & 3) == 1 ? &a1 : (j & 3) == 2 ? &a2 : &a3;
                    *ac = __builtin_amdgcn_mfma_f32_16x16x32_f16(ha[j], wA[c * 8 + j], *ac, 0, 0, 0);
                }
            }
            a0 = (a0 + a1) + (a2 + a3);

            *(f32x4*)(&gsp[w * 1024 + l * 4]) = a0;
            __syncthreads();

            float gi = gsp[gidx], gf = gsp[1024 + gidx],
                  gg = gsp[2048 + gidx], go = gsp[3072 + gidx];
            float cn = sigf(gf) * creg + sigf(gi) * tanh_c(gg);
            float hn = sigf(go) * tanh_c(cn);
            creg = cn;
            _Float16 hh = (_Float16)hn;
            unsigned short hu;
            __builtin_memcpy(&hu, &hh, 2);
            hstage[eb * 16 + ecol] = hu;
            __syncthreads();

            if (tid < 64 && pc < s - 2) {
                const unsigned* pp = prog + (size_t)(64 + tid) * 16;
                for (int it = 0; it < SPIN; ++it) {
                    unsigned v = ldg_u32_cc(pp);
                    if ((int)v >= s - 2) { pc = (int)v; break; }
                    __builtin_amdgcn_s_sleep(1);
                }
            }
            __syncthreads();
            if (w == 0 && l < CHK) {
                const unsigned* hsu = (const unsigned*)hstage;
                u32x4 pv;
                pv[0] = hsu[l * 3]; pv[1] = hsu[l * 3 + 1]; pv[2] = hsu[l * 3 + 2];
                pv[3] = (unsigned)(s + 1);
                stg_u4_cc(h2buf + (s & 3) * SLOTB + (size_t)(sb * CSTRIDE + l) * 16, pv);
            }
            if (w == 1 && l < 32) {
                half8 hv = *(const half8*)((const char*)hstage + l * 16);
                stg_h8_cc(h2seq + (size_t)(s * 16 + (l >> 1)) * HID + sb * 16 + (l & 1) * 8, hv);
            }
        }
        // final: certify all h2seq rows (<=255) visible, then join the pool
        asm volatile("s_waitcnt vmcnt(0)" ::: "memory");
        __syncthreads();
        if (tid == 0) stg_u32_cc(prog + 2048 + (size_t)sb * 16, 256u);
    }

    // rnn blocks join the logits GEMM work-steal pool
    if (logh) {
        __syncthreads();
        gemm_ws(h2seq, Wlog, blog, logh, prog2, wq, smem, tid);
    }
}

// ---------------- fused log-softmax, f32 in-place ----------------
__global__ __launch_bounds__(320) void k_lsm_f(float* __restrict__ logits) {
    int r = blockIdx.x, tid = threadIdx.x;
    float* row = logits + (size_t)r * VOC;
    f32x4 v[25];
    float m = -3.4e38f;
#pragma unroll
    for (int j = 0; j < 25; ++j) {
        v[j] = ((const f32x4*)row)[tid + 320 * j];
        m = fmaxf(fmaxf(fmaxf(m, v[j][0]), fmaxf(v[j][1], v[j][2])), v[j][3]);
    }
#pragma unroll
    for (int off = 1; off < 64; off <<= 1) m = fmaxf(m, __shfl_xor(m, off));
    __shared__ float sm[5], ssum[5];
    int wv = tid >> 6;
    if ((tid & 63) == 0) sm[wv] = m;
    __syncthreads();
    m = fmaxf(fmaxf(fmaxf(sm[0], sm[1]), fmaxf(sm[2], sm[3])), sm[4]);
    float s = 0.f;
#pragma unroll
    for (int j = 0; j < 25; ++j)
        s += (__expf(v[j][0] - m) + __expf(v[j][1] - m)) +
             (__expf(v[j][2] - m) + __expf(v[j][3] - m));
#pragma unroll
    for (int off = 1; off < 64; off <<= 1) s += __shfl_xor(s, off);
    if ((tid & 63) == 0) ssum[wv] = s;
    __syncthreads();
    s = (ssum[0] + ssum[1]) + (ssum[2] + ssum[3]) + ssum[4];
    float lse = m + __logf(s);
#pragma unroll
    for (int j = 0; j < 25; ++j) {
        f32x4 o = v[j];
        o[0] -= lse; o[1] -= lse; o[2] -= lse; o[3] -= lse;
        ((f32x4*)row)[tid + 320 * j] = o;
    }
}

// ---------------- fused log-softmax, f16 in -> f32 out ----------------
__global__ __launch_bounds__(320) void k_lsm_h(const _Float16* __restrict__ lg,
                                               float* __restrict__ out) {
    int r = blockIdx.x, tid = threadIdx.x;
    const half4* row = (const half4*)(lg + (size_t)r * VOC);
    float* orow = out + (size_t)r * VOC;
    half4 v[25];
    float m = -3.4e38f;
#pragma unroll
    for (int j = 0; j < 25; ++j) {
        v[j] = row[tid + 320 * j];
        float a = (float)v[j][0], b = (float)v[j][1], c = (float)v[j][2], d = (float)v[j][3];
        m = fmaxf(fmaxf(fmaxf(m, a), fmaxf(b, c)), d);
    }
#pragma unroll
    for (int off = 1; off < 64; off <<= 1) m = fmaxf(m, __shfl_xor(m, off));
    __shared__ float sm[5], ssum[5];
    int wv = tid >> 6;
    if ((tid & 63) == 0) sm[wv] = m;
    __syncthreads();
    m = fmaxf(fmaxf(fmaxf(sm[0], sm[1]), fmaxf(sm[2], sm[3])), sm[4]);
    float s = 0.f;
#pragma unroll
    for (int j = 0; j < 25; ++j)
        s += (__expf((float)v[j][0] - m) + __expf((float)v[j][1] - m)) +
             (__expf((float)v[j][2] - m) + __expf((float)v[j][3] - m));
#pragma unroll
    for (int off = 1; off < 64; off <<= 1) s += __shfl_xor(s, off);
    if ((tid & 63) == 0) ssum[wv] = s;
    __syncthreads();
    s = (ssum[0] + ssum[1]) + (ssum[2] + ssum[3]) + ssum[4];
    float lse = m + __logf(s);
#pragma unroll
    for (int j = 0; j < 25; ++j) {
        f32x4 o = {(float)v[j][0] - lse, (float)v[j][1] - lse,
                   (float)v[j][2] - lse, (float)v[j][3] - lse};
        ((f32x4*)orow)[tid + 320 * j] = o;
    }
}

// ---------------- launch ----------------
extern "C" void kernel_launch(void* const* d_in, const int* in_sizes, int n_in,
                              void* d_out, int out_size, void* d_ws, size_t ws_size,
                              hipStream_t stream) {
    const int*   tok   = (const int*)d_in[0];
    const float* emb   = (const float*)d_in[1];
    const float* W_ih1 = (const float*)d_in[2];
    const float* W_hh1 = (const float*)d_in[3];
    const float* b_ih1 = (const float*)d_in[4];
    const float* b_hh1 = (const float*)d_in[5];
    const float* W_ih2 = (const float*)d_in[6];
    const float* W_hh2 = (const float*)d_in[7];
    const float* b_ih2 = (const float*)d_in[8];
    const float* b_hh2 = (const float*)d_in[9];
    const float* W_log = (const float*)d_in[10];
    const float* b_log = (const float*)d_in[11];
    float* out = (float*)d_out;

    char* w = (char*)d_ws;
    auto alloc = [&](size_t bytes) {
        char* p = w;
        w += (bytes + 255) & ~(size_t)255;
        return p;
    };
    _Float16* Wih1h = (_Float16*)alloc((size_t)4096 * 512 * 2);
    _Float16* Whh1h = (_Float16*)alloc((size_t)4096 * 1024 * 2);
    _Float16* Wih2h = (_Float16*)alloc((size_t)4096 * 1024 * 2);
    _Float16* Whh2h = (_Float16*)alloc((size_t)4096 * 1024 * 2);
    _Float16* Wlogh = (_Float16*)alloc((size_t)VOC * 1024 * 2);
    _Float16* Abuf  = (_Float16*)alloc((size_t)4096 * 512 * 2);
    _Float16* Xh    = (_Float16*)alloc((size_t)4096 * 4096 * 2);
    _Float16* h2seq = (_Float16*)alloc((size_t)4096 * 1024 * 2);
    float* b1s      = (float*)alloc(4096 * 4);
    float* b2s      = (float*)alloc(4096 * 4);
    char* h1buf     = alloc(NS * SLOTB);    // 256 KB tag-chunk quad buffer
    char* h2buf     = alloc(NS * SLOTB);    // 256 KB
    unsigned* prog  = (unsigned*)alloc(12544);   // prog(8K) + prog2(4K) + wq
    size_t need = (size_t)(w - (char*)d_ws) + (size_t)NROW * VOC * 2;
    _Float16* logh = (need <= ws_size) ? (_Float16*)alloc((size_t)NROW * VOC * 2) : nullptr;

    // zero tag-chunk buffers + flags + work-queue (graph-replay safe)
    k_zero<<<64, 256, 0, stream>>>((float*)h1buf, (2 * NS * SLOTB + 12544) / 4);

    // all weight conversions f32 -> f16 in one dispatch (idempotent)
    k_cvt_all<<<2048, 256, 0, stream>>>(W_ih1, W_hh1, W_ih2, W_hh2, W_log,
                                        Wih1h, Whh1h, Wih2h, Whh2h, Wlogh);
    k_bias<<<16, 256, 0, stream>>>(b_ih1, b_hh1, b_ih2, b_hh2, b1s, b2s);

    // X1 = embed @ W_ih1^T + (b_ih1 + b_hh1), f16 out (256x256 pipelined)
    k_embed<<<2048, 256, 0, stream>>>(tok, emb, Abuf);
    k_gemm8<1><<<dim3(16, 16), 512, 0, stream>>>(Abuf, Wih1h, b1s, nullptr, Xh,
                                                 4096, 4096, 512, 0, 0, 0);

    if (logh) {
        // fused: recurrence (128 blocks) + work-steal logits GEMM (all 256)
        k_fused<<<256, 256, 0, stream>>>(Xh, Whh1h, Wih2h, Whh2h, b2s,
                                         h1buf, h2buf, prog, h2seq,
                                         Wlogh, b_log, logh);
        k_lsm_h<<<4096, 320, 0, stream>>>(logh, out);
    } else {
        k_fused<<<128, 256, 0, stream>>>(Xh, Whh1h, Wih2h, Whh2h, b2s,
                                         h1buf, h2buf, prog, h2seq,
                                         Wlogh, b_log, nullptr);
        k_gemm8<0><<<dim3(VOC / 256, 16), 512, 0, stream>>>(h2seq, Wlogh, b_log,
                                                            out, nullptr,
                                                            4096, VOC, 1024, 1, 0, 0);
        k_lsm_f<<<4096, 320, 0, stream>>>(out);
    }
}